// Round 2
// baseline (309.889 us; speedup 1.0000x reference)
//
#include <hip/hip_runtime.h>
#include <cstdint>
#include <cstddef>

// Problem constants: B=2, T=2048, D=1024, H=16, HD=64
typedef __bf16 bf16x8 __attribute__((ext_vector_type(8)));
typedef float  f32x4  __attribute__((ext_vector_type(4)));

#define DEV __device__ __forceinline__

DEV unsigned short f2bf(float f) {
  union { float f; unsigned u; } x; x.f = f;
  unsigned r = x.u + 0x7fffu + ((x.u >> 16) & 1u);   // round-to-nearest-even
  return (unsigned short)(r >> 16);
}

DEV void gl_lds16(const void* g, void* l) {
  __builtin_amdgcn_global_load_lds((const __attribute__((address_space(1))) void*)g,
                                   (__attribute__((address_space(3))) void*)l, 16, 0, 0);
}

DEV bf16x8 lds_frag(const void* base, int byteoff) {
  return *reinterpret_cast<const bf16x8*>(reinterpret_cast<const char*>(base) + byteoff);
}

DEV f32x4 MFMA(bf16x8 a, bf16x8 b, f32x4 c) {
  return __builtin_amdgcn_mfma_f32_16x16x32_bf16(a, b, c, 0, 0, 0);
}

// ---------------- x -> bf16 ----------------
__global__ __launch_bounds__(256) void k_cast_x(const float* __restrict__ x,
                                                unsigned short* __restrict__ xb) {
  int i = (blockIdx.x * 256 + threadIdx.x) * 8;
  float4 a = *(const float4*)(x + i);
  float4 b = *(const float4*)(x + i + 4);
  uint4 o;
  o.x = (unsigned)f2bf(a.x) | ((unsigned)f2bf(a.y) << 16);
  o.y = (unsigned)f2bf(a.z) | ((unsigned)f2bf(a.w) << 16);
  o.z = (unsigned)f2bf(b.x) | ((unsigned)f2bf(b.y) << 16);
  o.w = (unsigned)f2bf(b.z) | ((unsigned)f2bf(b.w) << 16);
  *reinterpret_cast<uint4*>(xb + i) = o;
}

// ---------------- W (K x N, f32) -> W^T (N x K, bf16) for all 4 weights ----------------
__global__ __launch_bounds__(256) void k_trans_w(const float* __restrict__ Wq, const float* __restrict__ Wk,
                                                 const float* __restrict__ Wv, const float* __restrict__ Wo,
                                                 unsigned short* __restrict__ WT) {
  __shared__ float tile[32][33];
  int z = blockIdx.z;
  const float* W = (z == 0) ? Wq : ((z == 1) ? Wk : ((z == 2) ? Wv : Wo));
  unsigned short* out = WT + ((size_t)z << 20);
  int x = threadIdx.x, y = threadIdx.y;        // block (32,8)
  int gx = blockIdx.x * 32 + x;                // col n
  int gy = blockIdx.y * 32;                    // row k base
#pragma unroll
  for (int i = 0; i < 4; ++i) tile[y + i * 8][x] = W[(size_t)(gy + y + i * 8) * 1024 + gx];
  __syncthreads();
#pragma unroll
  for (int i = 0; i < 4; ++i)
    out[(size_t)(blockIdx.x * 32 + y + i * 8) * 1024 + gy + x] = f2bf(tile[x][y + i * 8]);
}

// ---------------- cos/sin table from freqs (T x 32) ----------------
__global__ __launch_bounds__(256) void k_cs(const float* __restrict__ freqs, float* __restrict__ tab) {
  int i = blockIdx.x * 256 + threadIdx.x;      // 0..65535
  float a = freqs[i];
  float s, c;
  sincosf(a, &s, &c);
  ((float2*)tab)[i] = make_float2(c, s);
}

// ---------------- QKV GEMM: xb(4096x1024) @ W -> q/k/v bf16 (B,T,H,HD), fused bias+RoPE ----------------
__global__ __launch_bounds__(256) void k_qkv(const unsigned short* __restrict__ xb,
                                             const unsigned short* __restrict__ WT,
                                             const float* __restrict__ bq,
                                             const float* __restrict__ bk,
                                             const float* __restrict__ bv,
                                             const float* __restrict__ tab,
                                             unsigned short* __restrict__ qws,
                                             unsigned short* __restrict__ kws,
                                             unsigned short* __restrict__ vws) {
  __shared__ __align__(16) unsigned short As[128 * 32];
  __shared__ __align__(16) unsigned short Bs[128 * 32];
  int t = threadIdx.x, w = t >> 6, l = t & 63;
  int z = blockIdx.z;
  int n0 = blockIdx.x * 128, m0 = blockIdx.y * 128;
  const unsigned short* Wz = WT + ((size_t)z << 20);
  int wm = w >> 1, wn = w & 1;
  f32x4 zero4 = {0.f, 0.f, 0.f, 0.f};
  f32x4 acc[4][4];
#pragma unroll
  for (int i = 0; i < 4; ++i)
#pragma unroll
    for (int j = 0; j < 4; ++j) acc[i][j] = zero4;

  int aoff[4], boff[4];
#pragma unroll
  for (int i = 0; i < 4; ++i) {
    aoff[i] = ((wm * 64 + i * 16 + (l & 15)) * 32 + ((l >> 4) * 8)) * 2;
    boff[i] = ((wn * 64 + i * 16 + (l & 15)) * 32 + ((l >> 4) * 8)) * 2;
  }
  int r0 = t >> 2, c0 = t & 3;                 // issue-0 chunk -> row/chunk-in-row
  char* la = (char*)As + w * 1024;
  char* lb = (char*)Bs + w * 1024;

  for (int k0 = 0; k0 < 1024; k0 += 32) {
    const char* ga0 = (const char*)xb + ((size_t)(m0 + r0) * 1024 + k0 + c0 * 8) * 2;
    const char* ga1 = (const char*)xb + ((size_t)(m0 + 64 + r0) * 1024 + k0 + c0 * 8) * 2;
    const char* gb0 = (const char*)Wz + ((size_t)(n0 + r0) * 1024 + k0 + c0 * 8) * 2;
    const char* gb1 = (const char*)Wz + ((size_t)(n0 + 64 + r0) * 1024 + k0 + c0 * 8) * 2;
    gl_lds16(ga0, la);
    gl_lds16(ga1, la + 4096);
    gl_lds16(gb0, lb);
    gl_lds16(gb1, lb + 4096);
    asm volatile("s_waitcnt vmcnt(0)" ::: "memory");
    __syncthreads();
    bf16x8 af[4], bfr[4];
#pragma unroll
    for (int i = 0; i < 4; ++i) af[i] = lds_frag(As, aoff[i]);
#pragma unroll
    for (int i = 0; i < 4; ++i) bfr[i] = lds_frag(Bs, boff[i]);
#pragma unroll
    for (int i = 0; i < 4; ++i)
#pragma unroll
      for (int jn = 0; jn < 4; ++jn) acc[i][jn] = MFMA(af[i], bfr[jn], acc[i][jn]);
    __syncthreads();
  }

  const float* bias = (z == 0) ? bq : ((z == 1) ? bk : bv);
  unsigned short* outp = (z == 0) ? qws : ((z == 1) ? kws : vws);
  bool doRope = (z < 2);
  int nb = n0 + wn * 64, mb = m0 + wm * 64;
#pragma unroll
  for (int i = 0; i < 4; ++i) {
#pragma unroll
    for (int jn = 0; jn < 4; ++jn) {
      int n = nb + jn * 16 + (l & 15);
      float bsv = bias[n];
      int hd = n & 63;
#pragma unroll
      for (int j = 0; j < 4; ++j) {
        int m = mb + i * 16 + ((l >> 4) << 2) + j;
        float val = acc[i][jn][j] + bsv;
        if (doRope) {
          int trow = m & 2047;
          float2 cs = ((const float2*)tab)[trow * 32 + (hd >> 1)];
          float part = __shfl_xor(val, 1);
          val = (hd & 1) ? fmaf(part, cs.y, val * cs.x) : fmaf(val, cs.x, -part * cs.y);
        }
        outp[(size_t)m * 1024 + n] = f2bf(val);
      }
    }
  }
}

// ---------------- V (B,T,H,HD) -> V^T (B,H,HD,T) ----------------
__global__ __launch_bounds__(256) void k_vtrans(const unsigned short* __restrict__ vb,
                                                unsigned short* __restrict__ vtb) {
  __shared__ unsigned short vt[64 * 72];
  int t = threadIdx.x;
  int tt = blockIdx.x, bh = blockIdx.y;
  int b = bh >> 4, h = bh & 15;
  int row = t >> 2, ch = t & 3;
  const char* src = (const char*)vb + (((size_t)(b * 2048 + tt * 64 + row) * 1024) + h * 64 + ch * 16) * 2;
  uint4 v0 = *(const uint4*)src;
  uint4 v1 = *(const uint4*)(src + 16);
  const unsigned short* e0 = (const unsigned short*)&v0;
  const unsigned short* e1 = (const unsigned short*)&v1;
#pragma unroll
  for (int i = 0; i < 8; ++i) vt[(ch * 16 + i) * 72 + row] = e0[i];
#pragma unroll
  for (int i = 0; i < 8; ++i) vt[(ch * 16 + 8 + i) * 72 + row] = e1[i];
  __syncthreads();
  int hd = t >> 2, c2 = t & 3;
  uint4 o0 = *(const uint4*)&vt[hd * 72 + c2 * 16];
  uint4 o1 = *(const uint4*)&vt[hd * 72 + c2 * 16 + 8];
  char* dst = (char*)vtb + (((size_t)(bh * 64 + hd) * 2048) + tt * 64 + c2 * 16) * 2;
  *(uint4*)dst = o0;
  *(uint4*)(dst + 16) = o1;
}

// ---------------- Flash attention (causal), 64 q-rows/block, KV tiles of 64 ----------------
__global__ __launch_bounds__(256) void k_attn(const unsigned short* __restrict__ qb,
                                              const unsigned short* __restrict__ kb,
                                              const unsigned short* __restrict__ vtb,
                                              unsigned short* __restrict__ ab) {
  __shared__ __align__(16) unsigned short Ks[64 * 64];
  __shared__ __align__(16) unsigned short Vts[64 * 64];
  __shared__ __align__(16) unsigned short Ps[4 * 16 * 64];
  int t = threadIdx.x, w = t >> 6, l = t & 63;
  int qt = gridDim.x - 1 - blockIdx.x;         // heavy blocks first
  int bh = blockIdx.y;
  int b = bh >> 4, h = bh & 15;
  const float KL2E = 0.18033688011112042f;     // log2(e)/sqrt(64)

  bf16x8 qf[2];
  {
    int m = b * 2048 + qt * 64 + w * 16 + (l & 15);
    const char* qp = (const char*)qb + ((size_t)m * 1024 + h * 64 + ((l >> 4) * 8)) * 2;
    qf[0] = *(const bf16x8*)qp;
    qf[1] = *(const bf16x8*)(qp + 64);
  }
  f32x4 zero4 = {0.f, 0.f, 0.f, 0.f};
  f32x4 po[4];
#pragma unroll
  for (int i = 0; i < 4; ++i) po[i] = zero4;
  float m_run[4] = {-1e30f, -1e30f, -1e30f, -1e30f};
  float l_run[4] = {0.f, 0.f, 0.f, 0.f};
  unsigned short* pw = Ps + w * 1024;
  int r0 = t >> 3, s0 = t & 7;
  int lc0 = s0 ^ (r0 & 7);
  int r1 = (256 + t) >> 3, s1 = t & 7;
  int lc1 = s1 ^ (r1 & 7);
  char* lk = (char*)Ks + w * 1024;
  char* lv = (char*)Vts + w * 1024;

  for (int jt = 0; jt <= qt; ++jt) {
    {
      const char* gk0 = (const char*)kb + ((size_t)(b * 2048 + jt * 64 + r0) * 1024 + h * 64 + lc0 * 8) * 2;
      const char* gk1 = (const char*)kb + ((size_t)(b * 2048 + jt * 64 + r1) * 1024 + h * 64 + lc1 * 8) * 2;
      const char* gv0 = (const char*)vtb + ((size_t)(bh * 64 + r0) * 2048 + jt * 64 + lc0 * 8) * 2;
      const char* gv1 = (const char*)vtb + ((size_t)(bh * 64 + r1) * 2048 + jt * 64 + lc1 * 8) * 2;
      gl_lds16(gk0, lk);
      gl_lds16(gk1, lk + 4096);
      gl_lds16(gv0, lv);
      gl_lds16(gv1, lv + 4096);
    }
    asm volatile("s_waitcnt vmcnt(0)" ::: "memory");
    __syncthreads();

    // S = Q K^T (16 q-rows x 64 kv per wave)
    f32x4 ps[4];
#pragma unroll
    for (int bn = 0; bn < 4; ++bn) ps[bn] = zero4;
#pragma unroll
    for (int ks = 0; ks < 2; ++ks) {
#pragma unroll
      for (int bn = 0; bn < 4; ++bn) {
        int row = bn * 16 + (l & 15);
        bf16x8 kf = lds_frag(Ks, row * 128 + (((ks * 4 + (l >> 4)) ^ (row & 7)) << 4));
        ps[bn] = MFMA(qf[ks], kf, ps[bn]);
      }
    }
    if (jt == qt) {                            // diagonal tile: causal mask
#pragma unroll
      for (int bn = 0; bn < 4; ++bn) {
        int kv = bn * 16 + (l & 15);
#pragma unroll
        for (int j = 0; j < 4; ++j) {
          int r = ((l >> 4) << 2) + j;
          if (kv > w * 16 + r) ps[bn][j] = -1e30f;
        }
      }
    }
    // online softmax
    float rm[4];
#pragma unroll
    for (int j = 0; j < 4; ++j)
      rm[j] = fmaxf(fmaxf(ps[0][j], ps[1][j]), fmaxf(ps[2][j], ps[3][j]));
#pragma unroll
    for (int off = 1; off < 16; off <<= 1)
#pragma unroll
      for (int j = 0; j < 4; ++j) rm[j] = fmaxf(rm[j], __shfl_xor(rm[j], off));
    float alpha[4], rs[4];
#pragma unroll
    for (int j = 0; j < 4; ++j) {
      float mn = fmaxf(m_run[j], rm[j]);
      alpha[j] = exp2f((m_run[j] - mn) * KL2E);
      m_run[j] = mn;
      rs[j] = 0.f;
    }
#pragma unroll
    for (int bn = 0; bn < 4; ++bn)
#pragma unroll
      for (int j = 0; j < 4; ++j) {
        float p = exp2f((ps[bn][j] - m_run[j]) * KL2E);
        ps[bn][j] = p;
        rs[j] += p;
      }
#pragma unroll
    for (int off = 1; off < 16; off <<= 1)
#pragma unroll
      for (int j = 0; j < 4; ++j) rs[j] += __shfl_xor(rs[j], off);
#pragma unroll
    for (int j = 0; j < 4; ++j) l_run[j] = l_run[j] * alpha[j] + rs[j];
#pragma unroll
    for (int hf = 0; hf < 4; ++hf)
#pragma unroll
      for (int j = 0; j < 4; ++j) po[hf][j] *= alpha[j];
    // P -> LDS (swizzled) for the PV A-operand
#pragma unroll
    for (int bn = 0; bn < 4; ++bn)
#pragma unroll
      for (int j = 0; j < 4; ++j) {
        int r = ((l >> 4) << 2) + j, c = bn * 16 + (l & 15);
        pw[r * 64 + (((c >> 3) ^ (r & 7)) << 3) + (c & 7)] = f2bf(ps[bn][j]);
      }
    asm volatile("" ::: "memory");
    // O += P V
#pragma unroll
    for (int ks = 0; ks < 2; ++ks) {
      int prow = l & 15;
      bf16x8 pa = lds_frag(pw, prow * 128 + (((ks * 4 + (l >> 4)) ^ (prow & 7)) << 4));
#pragma unroll
      for (int hf = 0; hf < 4; ++hf) {
        int vrow = hf * 16 + (l & 15);
        bf16x8 vf = lds_frag(Vts, vrow * 128 + (((ks * 4 + (l >> 4)) ^ (vrow & 7)) << 4));
        po[hf] = MFMA(pa, vf, po[hf]);
      }
    }
    __syncthreads();
  }
  float inv[4];
#pragma unroll
  for (int j = 0; j < 4; ++j) inv[j] = 1.0f / l_run[j];
#pragma unroll
  for (int hf = 0; hf < 4; ++hf)
#pragma unroll
    for (int j = 0; j < 4; ++j) {
      int r = ((l >> 4) << 2) + j;
      int m = b * 2048 + qt * 64 + w * 16 + r;
      int col = h * 64 + hf * 16 + (l & 15);
      ab[(size_t)m * 1024 + col] = f2bf(po[hf][j] * inv[j]);
    }
}

// ---------------- Output projection: ab @ Wo + bo -> fp32 out ----------------
__global__ __launch_bounds__(256) void k_oproj(const unsigned short* __restrict__ ab,
                                               const unsigned short* __restrict__ WoT,
                                               const float* __restrict__ bo,
                                               float* __restrict__ out) {
  __shared__ __align__(16) unsigned short As[128 * 32];
  __shared__ __align__(16) unsigned short Bs[128 * 32];
  int t = threadIdx.x, w = t >> 6, l = t & 63;
  int n0 = blockIdx.x * 128, m0 = blockIdx.y * 128;
  int wm = w >> 1, wn = w & 1;
  f32x4 zero4 = {0.f, 0.f, 0.f, 0.f};
  f32x4 acc[4][4];
#pragma unroll
  for (int i = 0; i < 4; ++i)
#pragma unroll
    for (int j = 0; j < 4; ++j) acc[i][j] = zero4;
  int aoff[4], boff[4];
#pragma unroll
  for (int i = 0; i < 4; ++i) {
    aoff[i] = ((wm * 64 + i * 16 + (l & 15)) * 32 + ((l >> 4) * 8)) * 2;
    boff[i] = ((wn * 64 + i * 16 + (l & 15)) * 32 + ((l >> 4) * 8)) * 2;
  }
  int r0 = t >> 2, c0 = t & 3;
  char* la = (char*)As + w * 1024;
  char* lb = (char*)Bs + w * 1024;
  for (int k0 = 0; k0 < 1024; k0 += 32) {
    const char* ga0 = (const char*)ab + ((size_t)(m0 + r0) * 1024 + k0 + c0 * 8) * 2;
    const char* ga1 = (const char*)ab + ((size_t)(m0 + 64 + r0) * 1024 + k0 + c0 * 8) * 2;
    const char* gb0 = (const char*)WoT + ((size_t)(n0 + r0) * 1024 + k0 + c0 * 8) * 2;
    const char* gb1 = (const char*)WoT + ((size_t)(n0 + 64 + r0) * 1024 + k0 + c0 * 8) * 2;
    gl_lds16(ga0, la);
    gl_lds16(ga1, la + 4096);
    gl_lds16(gb0, lb);
    gl_lds16(gb1, lb + 4096);
    asm volatile("s_waitcnt vmcnt(0)" ::: "memory");
    __syncthreads();
    bf16x8 af[4], bfr[4];
#pragma unroll
    for (int i = 0; i < 4; ++i) af[i] = lds_frag(As, aoff[i]);
#pragma unroll
    for (int i = 0; i < 4; ++i) bfr[i] = lds_frag(Bs, boff[i]);
#pragma unroll
    for (int i = 0; i < 4; ++i)
#pragma unroll
      for (int jn = 0; jn < 4; ++jn) acc[i][jn] = MFMA(af[i], bfr[jn], acc[i][jn]);
    __syncthreads();
  }
  int nb = n0 + wn * 64, mb = m0 + wm * 64;
#pragma unroll
  for (int i = 0; i < 4; ++i)
#pragma unroll
    for (int jn = 0; jn < 4; ++jn) {
      int n = nb + jn * 16 + (l & 15);
      float bsv = bo[n];
#pragma unroll
      for (int j = 0; j < 4; ++j) {
        int m = mb + i * 16 + ((l >> 4) << 2) + j;
        out[(size_t)m * 1024 + n] = acc[i][jn][j] + bsv;
      }
    }
}

extern "C" void kernel_launch(void* const* d_in, const int* in_sizes, int n_in,
                              void* d_out, int out_size, void* d_ws, size_t ws_size,
                              hipStream_t stream) {
  const float* x     = (const float*)d_in[0];
  // d_in[1] = mask (causal tril, implemented analytically)
  const float* freqs = (const float*)d_in[2];
  const float* Wq    = (const float*)d_in[3];
  const float* bq    = (const float*)d_in[4];
  const float* Wk    = (const float*)d_in[5];
  const float* bk    = (const float*)d_in[6];
  const float* Wv    = (const float*)d_in[7];
  const float* bv    = (const float*)d_in[8];
  const float* Wo    = (const float*)d_in[9];
  const float* bo    = (const float*)d_in[10];

  char* ws = (char*)d_ws;
  unsigned short* xb  = (unsigned short*)(ws);
  unsigned short* WT  = (unsigned short*)(ws + ((size_t)8 << 20));
  unsigned short* qb  = (unsigned short*)(ws + ((size_t)16 << 20));
  unsigned short* kb  = (unsigned short*)(ws + ((size_t)24 << 20));
  unsigned short* vb  = (unsigned short*)(ws + ((size_t)32 << 20));
  unsigned short* vtb = (unsigned short*)(ws + ((size_t)40 << 20));
  unsigned short* ab  = (unsigned short*)(ws + ((size_t)48 << 20));
  float*          tab = (float*)(ws + ((size_t)56 << 20));

  k_cast_x<<<2048, 256, 0, stream>>>(x, xb);
  k_trans_w<<<dim3(32, 32, 4), dim3(32, 8), 0, stream>>>(Wq, Wk, Wv, Wo, WT);
  k_cs<<<256, 256, 0, stream>>>(freqs, tab);
  k_qkv<<<dim3(8, 32, 3), 256, 0, stream>>>(xb, WT, bq, bk, bv, tab, qb, kb, vb);
  k_vtrans<<<dim3(32, 32), 256, 0, stream>>>(vb, vtb);
  k_attn<<<dim3(32, 32), 256, 0, stream>>>(qb, kb, vtb, ab);
  k_oproj<<<dim3(8, 32), 256, 0, stream>>>(ab, WT + ((size_t)3 << 20), bo, (float*)d_out);
}

// Round 4
// 273.559 us; speedup vs baseline: 1.1328x; 1.1328x over previous
//
#include <hip/hip_runtime.h>
#include <cstdint>
#include <cstddef>

// Problem constants: B=2, T=2048, D=1024, H=16, HD=64
typedef __bf16 bf16x8 __attribute__((ext_vector_type(8)));
typedef float  f32x4  __attribute__((ext_vector_type(4)));

#define DEV __device__ __forceinline__

DEV unsigned short f2bf(float f) {
  union { float f; unsigned u; } x; x.f = f;
  unsigned r = x.u + 0x7fffu + ((x.u >> 16) & 1u);   // round-to-nearest-even
  return (unsigned short)(r >> 16);
}

DEV void gl_lds16(const void* g, void* l) {
  __builtin_amdgcn_global_load_lds((const __attribute__((address_space(1))) void*)g,
                                   (__attribute__((address_space(3))) void*)l, 16, 0, 0);
}

DEV bf16x8 lds_frag(const void* base, int byteoff) {
  return *reinterpret_cast<const bf16x8*>(reinterpret_cast<const char*>(base) + byteoff);
}

DEV f32x4 MFMA(bf16x8 a, bf16x8 b, f32x4 c) {
  return __builtin_amdgcn_mfma_f32_16x16x32_bf16(a, b, c, 0, 0, 0);
}

// ---------------- x -> bf16 ----------------
__global__ __launch_bounds__(256) void k_cast_x(const float* __restrict__ x,
                                                unsigned short* __restrict__ xb) {
  int i = (blockIdx.x * 256 + threadIdx.x) * 8;
  float4 a = *(const float4*)(x + i);
  float4 b = *(const float4*)(x + i + 4);
  uint4 o;
  o.x = (unsigned)f2bf(a.x) | ((unsigned)f2bf(a.y) << 16);
  o.y = (unsigned)f2bf(a.z) | ((unsigned)f2bf(a.w) << 16);
  o.z = (unsigned)f2bf(b.x) | ((unsigned)f2bf(b.y) << 16);
  o.w = (unsigned)f2bf(b.z) | ((unsigned)f2bf(b.w) << 16);
  *reinterpret_cast<uint4*>(xb + i) = o;
}

// ---------------- W (K x N, f32) -> W^T (N x K, bf16) for all 4 weights ----------------
__global__ __launch_bounds__(256) void k_trans_w(const float* __restrict__ Wq, const float* __restrict__ Wk,
                                                 const float* __restrict__ Wv, const float* __restrict__ Wo,
                                                 unsigned short* __restrict__ WT) {
  __shared__ float tile[32][33];
  int z = blockIdx.z;
  const float* W = (z == 0) ? Wq : ((z == 1) ? Wk : ((z == 2) ? Wv : Wo));
  unsigned short* out = WT + ((size_t)z << 20);
  int x = threadIdx.x, y = threadIdx.y;        // block (32,8)
  int gx = blockIdx.x * 32 + x;                // col n
  int gy = blockIdx.y * 32;                    // row k base
#pragma unroll
  for (int i = 0; i < 4; ++i) tile[y + i * 8][x] = W[(size_t)(gy + y + i * 8) * 1024 + gx];
  __syncthreads();
#pragma unroll
  for (int i = 0; i < 4; ++i)
    out[(size_t)(blockIdx.x * 32 + y + i * 8) * 1024 + gy + x] = f2bf(tile[x][y + i * 8]);
}

// ---------------- cos/sin table from freqs (T x 32) ----------------
__global__ __launch_bounds__(256) void k_cs(const float* __restrict__ freqs, float* __restrict__ tab) {
  int i = blockIdx.x * 256 + threadIdx.x;      // 0..65535
  float a = freqs[i];
  float s, c;
  sincosf(a, &s, &c);
  ((float2*)tab)[i] = make_float2(c, s);
}

// ---------------- QKV GEMM (dbuf): xb(4096x1024) @ W -> q/k bf16 (+RoPE), V -> V^T direct ----------------
__global__ __launch_bounds__(256) void k_qkv(const unsigned short* __restrict__ xb,
                                             const unsigned short* __restrict__ WT,
                                             const float* __restrict__ bq,
                                             const float* __restrict__ bk,
                                             const float* __restrict__ bv,
                                             const float* __restrict__ tab,
                                             unsigned short* __restrict__ qws,
                                             unsigned short* __restrict__ kws,
                                             unsigned short* __restrict__ vtb) {
  __shared__ __align__(16) unsigned short As[2][128 * 32];
  __shared__ __align__(16) unsigned short Bs[2][128 * 32];
  int t = threadIdx.x, w = t >> 6, l = t & 63;
  int z = blockIdx.z;
  int n0 = blockIdx.x * 128, m0 = blockIdx.y * 128;
  const unsigned short* Wz = WT + ((size_t)z << 20);
  int wm = w >> 1, wn = w & 1;
  f32x4 zero4 = {0.f, 0.f, 0.f, 0.f};
  f32x4 acc[4][4];
#pragma unroll
  for (int i = 0; i < 4; ++i)
#pragma unroll
    for (int j = 0; j < 4; ++j) acc[i][j] = zero4;

  int aoff[4], boff[4];
#pragma unroll
  for (int i = 0; i < 4; ++i) {
    aoff[i] = ((wm * 64 + i * 16 + (l & 15)) * 32 + ((l >> 4) * 8)) * 2;
    boff[i] = ((wn * 64 + i * 16 + (l & 15)) * 32 + ((l >> 4) * 8)) * 2;
  }
  int r0 = t >> 2, c0 = t & 3;

#define QSTAGE(k0v, buf) do { \
    char* la = (char*)As + (buf) * 8192 + w * 1024; \
    char* lb = (char*)Bs + (buf) * 8192 + w * 1024; \
    const char* ga0 = (const char*)xb + ((size_t)(m0 + r0) * 1024 + (k0v) + c0 * 8) * 2; \
    const char* ga1 = (const char*)xb + ((size_t)(m0 + 64 + r0) * 1024 + (k0v) + c0 * 8) * 2; \
    const char* gb0 = (const char*)Wz + ((size_t)(n0 + r0) * 1024 + (k0v) + c0 * 8) * 2; \
    const char* gb1 = (const char*)Wz + ((size_t)(n0 + 64 + r0) * 1024 + (k0v) + c0 * 8) * 2; \
    gl_lds16(ga0, la); gl_lds16(ga1, la + 4096); \
    gl_lds16(gb0, lb); gl_lds16(gb1, lb + 4096); \
  } while (0)

  QSTAGE(0, 0);
  asm volatile("s_waitcnt vmcnt(0)" ::: "memory");
  __syncthreads();
  for (int k0 = 0; k0 < 1024; k0 += 32) {
    int cur = (k0 >> 5) & 1;
    if (k0 + 32 < 1024) QSTAGE(k0 + 32, cur ^ 1);
    const char* Ab = (const char*)As + cur * 8192;
    const char* Bb = (const char*)Bs + cur * 8192;
    bf16x8 af[4], bfr[4];
#pragma unroll
    for (int i = 0; i < 4; ++i) af[i] = lds_frag(Ab, aoff[i]);
#pragma unroll
    for (int i = 0; i < 4; ++i) bfr[i] = lds_frag(Bb, boff[i]);
#pragma unroll
    for (int i = 0; i < 4; ++i)
#pragma unroll
      for (int jn = 0; jn < 4; ++jn) acc[i][jn] = MFMA(af[i], bfr[jn], acc[i][jn]);
    asm volatile("s_waitcnt vmcnt(0)" ::: "memory");
    __syncthreads();
  }
#undef QSTAGE

  int nb = n0 + wn * 64, mb = m0 + wm * 64;
  if (z == 2) {
    // V: write V^T (B,H,HD,T) directly, fused transpose
#pragma unroll
    for (int i = 0; i < 4; ++i)
#pragma unroll
      for (int jn = 0; jn < 4; ++jn) {
        int n = nb + jn * 16 + (l & 15);
        float bsv = bv[n];
        int hh = n >> 6, hd = n & 63;
        int m0j = mb + i * 16 + ((l >> 4) << 2);
        int bb = m0j >> 11, tt = m0j & 2047;
        ushort4 pk;
        pk.x = f2bf(acc[i][jn][0] + bsv);
        pk.y = f2bf(acc[i][jn][1] + bsv);
        pk.z = f2bf(acc[i][jn][2] + bsv);
        pk.w = f2bf(acc[i][jn][3] + bsv);
        *(ushort4*)&vtb[(((size_t)(bb * 16 + hh) * 64 + hd) * 2048) + tt] = pk;
      }
  } else {
    const float* bias = (z == 0) ? bq : bk;
    unsigned short* outp = (z == 0) ? qws : kws;
#pragma unroll
    for (int i = 0; i < 4; ++i)
#pragma unroll
      for (int jn = 0; jn < 4; ++jn) {
        int n = nb + jn * 16 + (l & 15);
        float bsv = bias[n];
        int hd = n & 63;
#pragma unroll
        for (int j = 0; j < 4; ++j) {
          int m = mb + i * 16 + ((l >> 4) << 2) + j;
          float val = acc[i][jn][j] + bsv;
          int trow = m & 2047;
          float2 cs = ((const float2*)tab)[trow * 32 + (hd >> 1)];
          float part = __shfl_xor(val, 1);
          val = (hd & 1) ? fmaf(part, cs.y, val * cs.x) : fmaf(val, cs.x, -part * cs.y);
          outp[(size_t)m * 1024 + n] = f2bf(val);
        }
      }
  }
}

// ---------------- attention strip compute (one 16-q-row x 64-kv tile step) ----------------
DEV void attn_strip(const bf16x8 (&qf)[2], f32x4 (&po)[4], float (&m_run)[4], float (&l_run)[4],
                    bool diag, const char* Kb, const char* Vb, unsigned short* pw, int w, int l) {
  const float KL2E = 0.18033688011112042f;     // log2(e)/sqrt(64)
  f32x4 zero4 = {0.f, 0.f, 0.f, 0.f};
  f32x4 ps[4];
#pragma unroll
  for (int bn = 0; bn < 4; ++bn) ps[bn] = zero4;
  __builtin_amdgcn_s_setprio(1);
#pragma unroll
  for (int ks = 0; ks < 2; ++ks)
#pragma unroll
    for (int bn = 0; bn < 4; ++bn) {
      int row = bn * 16 + (l & 15);
      bf16x8 kf = lds_frag(Kb, row * 128 + (((ks * 4 + (l >> 4)) ^ (row & 7)) << 4));
      ps[bn] = MFMA(qf[ks], kf, ps[bn]);
    }
  __builtin_amdgcn_s_setprio(0);
  if (diag) {
#pragma unroll
    for (int bn = 0; bn < 4; ++bn) {
      int kv = bn * 16 + (l & 15);
#pragma unroll
      for (int j = 0; j < 4; ++j) {
        int r = ((l >> 4) << 2) + j;
        if (kv > w * 16 + r) ps[bn][j] = -1e30f;
      }
    }
  }
  float rm[4];
#pragma unroll
  for (int j = 0; j < 4; ++j)
    rm[j] = fmaxf(fmaxf(ps[0][j], ps[1][j]), fmaxf(ps[2][j], ps[3][j]));
#pragma unroll
  for (int off = 1; off < 16; off <<= 1)
#pragma unroll
    for (int j = 0; j < 4; ++j) rm[j] = fmaxf(rm[j], __shfl_xor(rm[j], off));
  float alpha[4], rs[4];
#pragma unroll
  for (int j = 0; j < 4; ++j) {
    float mn = fmaxf(m_run[j], rm[j]);
    alpha[j] = exp2f((m_run[j] - mn) * KL2E);
    m_run[j] = mn;
    rs[j] = 0.f;
  }
#pragma unroll
  for (int bn = 0; bn < 4; ++bn)
#pragma unroll
    for (int j = 0; j < 4; ++j) {
      float p = exp2f((ps[bn][j] - m_run[j]) * KL2E);
      ps[bn][j] = p;
      rs[j] += p;
    }
#pragma unroll
  for (int off = 1; off < 16; off <<= 1)
#pragma unroll
    for (int j = 0; j < 4; ++j) rs[j] += __shfl_xor(rs[j], off);
#pragma unroll
  for (int j = 0; j < 4; ++j) l_run[j] = l_run[j] * alpha[j] + rs[j];
#pragma unroll
  for (int hf = 0; hf < 4; ++hf)
#pragma unroll
    for (int j = 0; j < 4; ++j) po[hf][j] *= alpha[j];
  // P -> LDS (swizzled) for the PV A-operand
#pragma unroll
  for (int bn = 0; bn < 4; ++bn)
#pragma unroll
    for (int j = 0; j < 4; ++j) {
      int r = ((l >> 4) << 2) + j, c = bn * 16 + (l & 15);
      pw[r * 64 + (((c >> 3) ^ (r & 7)) << 3) + (c & 7)] = f2bf(ps[bn][j]);
    }
  asm volatile("" ::: "memory");
  __builtin_amdgcn_s_setprio(1);
#pragma unroll
  for (int ks = 0; ks < 2; ++ks) {
    int prow = l & 15;
    bf16x8 pa = lds_frag(pw, prow * 128 + (((ks * 4 + (l >> 4)) ^ (prow & 7)) << 4));
#pragma unroll
    for (int hf = 0; hf < 4; ++hf) {
      int vrow = hf * 16 + (l & 15);
      bf16x8 vf = lds_frag(Vb, vrow * 128 + (((ks * 4 + (l >> 4)) ^ (vrow & 7)) << 4));
      po[hf] = MFMA(pa, vf, po[hf]);
    }
  }
  __builtin_amdgcn_s_setprio(0);
  asm volatile("" ::: "memory");
}

// ---------------- Flash attention (causal), paired strips, dbuf KV, XCD-clustered ----------------
__global__ __launch_bounds__(256) void k_attn(const unsigned short* __restrict__ qb,
                                              const unsigned short* __restrict__ kb,
                                              const unsigned short* __restrict__ vtb,
                                              unsigned short* __restrict__ ab) {
  __shared__ __align__(16) unsigned short Ks[2][64 * 64];
  __shared__ __align__(16) unsigned short Vts[2][64 * 64];
  __shared__ __align__(16) unsigned short PsA[4 * 16 * 64];
  __shared__ __align__(16) unsigned short PsB[4 * 16 * 64];
  int t = threadIdx.x, w = t >> 6, l = t & 63;
  int lid = blockIdx.x;                        // 512 blocks
  int xcd = lid & 7, rest = lid >> 3;          // cluster same-bh on one XCD's L2
  int bh = xcd + 8 * (rest & 3);
  int pi = rest >> 2;                          // 0..15
  int qtA = pi, qtB = 31 - pi;                 // balanced causal pair: 33 strip-tiles/block
  int b = bh >> 4, h = bh & 15;

  bf16x8 qfA[2], qfB[2];
  {
    int mA = b * 2048 + qtA * 64 + w * 16 + (l & 15);
    const char* qp = (const char*)qb + ((size_t)mA * 1024 + h * 64 + ((l >> 4) * 8)) * 2;
    qfA[0] = *(const bf16x8*)qp;
    qfA[1] = *(const bf16x8*)(qp + 64);
    int mB = b * 2048 + qtB * 64 + w * 16 + (l & 15);
    const char* qp2 = (const char*)qb + ((size_t)mB * 1024 + h * 64 + ((l >> 4) * 8)) * 2;
    qfB[0] = *(const bf16x8*)qp2;
    qfB[1] = *(const bf16x8*)(qp2 + 64);
  }
  f32x4 zero4 = {0.f, 0.f, 0.f, 0.f};
  f32x4 poA[4], poB[4];
  float mA_[4], lA_[4], mB_[4], lB_[4];
#pragma unroll
  for (int i = 0; i < 4; ++i) {
    poA[i] = zero4; poB[i] = zero4;
    mA_[i] = -1e30f; lA_[i] = 0.f;
    mB_[i] = -1e30f; lB_[i] = 0.f;
  }
  unsigned short* pwA = PsA + w * 1024;
  unsigned short* pwB = PsB + w * 1024;
  int r0 = t >> 3, s0 = t & 7, lc0 = s0 ^ (r0 & 7);
  int r1 = 32 + r0;                            // (r1&7)==(r0&7) so lc1==lc0
  const char* kbase = (const char*)kb + ((size_t)(b * 2048) * 1024 + h * 64) * 2;
  const char* vbase = (const char*)vtb + ((size_t)bh * 64) * 2048 * 2;

#define ASTAGE(jt, buf) do { \
    char* lk = (char*)Ks + (buf) * 8192 + w * 1024; \
    char* lv = (char*)Vts + (buf) * 8192 + w * 1024; \
    const char* gk0 = kbase + ((size_t)((jt) * 64 + r0) * 1024) * 2 + lc0 * 16; \
    const char* gk1 = kbase + ((size_t)((jt) * 64 + r1) * 1024) * 2 + lc0 * 16; \
    const char* gv0 = vbase + (size_t)r0 * 4096 + (jt) * 128 + lc0 * 16; \
    const char* gv1 = vbase + (size_t)r1 * 4096 + (jt) * 128 + lc0 * 16; \
    gl_lds16(gk0, lk); gl_lds16(gk1, lk + 4096); \
    gl_lds16(gv0, lv); gl_lds16(gv1, lv + 4096); \
  } while (0)

  ASTAGE(0, 0);
  asm volatile("s_waitcnt vmcnt(0)" ::: "memory");
  __syncthreads();
  for (int jt = 0; jt <= qtB; ++jt) {
    int cur = jt & 1;
    if (jt < qtB) ASTAGE(jt + 1, cur ^ 1);     // prefetch overlaps compute below
    const char* Kb = (const char*)Ks + cur * 8192;
    const char* Vb = (const char*)Vts + cur * 8192;
    attn_strip(qfB, poB, mB_, lB_, jt == qtB, Kb, Vb, pwB, w, l);
    if (jt <= qtA) attn_strip(qfA, poA, mA_, lA_, jt == qtA, Kb, Vb, pwA, w, l);
    asm volatile("s_waitcnt vmcnt(0)" ::: "memory");
    __syncthreads();
  }
#undef ASTAGE

#pragma unroll
  for (int s = 0; s < 2; ++s) {
    f32x4* po = s ? poB : poA;
    float* lr = s ? lB_ : lA_;
    int qt = s ? qtB : qtA;
    float inv[4];
#pragma unroll
    for (int j = 0; j < 4; ++j) inv[j] = 1.0f / lr[j];
#pragma unroll
    for (int hf = 0; hf < 4; ++hf)
#pragma unroll
      for (int j = 0; j < 4; ++j) {
        int r = ((l >> 4) << 2) + j;
        int m = b * 2048 + qt * 64 + w * 16 + r;
        int col = h * 64 + hf * 16 + (l & 15);
        ab[(size_t)m * 1024 + col] = f2bf(po[hf][j] * inv[j]);
      }
  }
}

// ---------------- Output projection (dbuf): ab @ Wo + bo -> fp32 out ----------------
__global__ __launch_bounds__(256) void k_oproj(const unsigned short* __restrict__ ab,
                                               const unsigned short* __restrict__ WoT,
                                               const float* __restrict__ bo,
                                               float* __restrict__ out) {
  __shared__ __align__(16) unsigned short As[2][128 * 32];
  __shared__ __align__(16) unsigned short Bs[2][128 * 32];
  int t = threadIdx.x, w = t >> 6, l = t & 63;
  int n0 = blockIdx.x * 128, m0 = blockIdx.y * 128;
  int wm = w >> 1, wn = w & 1;
  f32x4 zero4 = {0.f, 0.f, 0.f, 0.f};
  f32x4 acc[4][4];
#pragma unroll
  for (int i = 0; i < 4; ++i)
#pragma unroll
    for (int j = 0; j < 4; ++j) acc[i][j] = zero4;
  int aoff[4], boff[4];
#pragma unroll
  for (int i = 0; i < 4; ++i) {
    aoff[i] = ((wm * 64 + i * 16 + (l & 15)) * 32 + ((l >> 4) * 8)) * 2;
    boff[i] = ((wn * 64 + i * 16 + (l & 15)) * 32 + ((l >> 4) * 8)) * 2;
  }
  int r0 = t >> 2, c0 = t & 3;

#define OSTAGE(k0v, buf) do { \
    char* la = (char*)As + (buf) * 8192 + w * 1024; \
    char* lb = (char*)Bs + (buf) * 8192 + w * 1024; \
    const char* ga0 = (const char*)ab + ((size_t)(m0 + r0) * 1024 + (k0v) + c0 * 8) * 2; \
    const char* ga1 = (const char*)ab + ((size_t)(m0 + 64 + r0) * 1024 + (k0v) + c0 * 8) * 2; \
    const char* gb0 = (const char*)WoT + ((size_t)(n0 + r0) * 1024 + (k0v) + c0 * 8) * 2; \
    const char* gb1 = (const char*)WoT + ((size_t)(n0 + 64 + r0) * 1024 + (k0v) + c0 * 8) * 2; \
    gl_lds16(ga0, la); gl_lds16(ga1, la + 4096); \
    gl_lds16(gb0, lb); gl_lds16(gb1, lb + 4096); \
  } while (0)

  OSTAGE(0, 0);
  asm volatile("s_waitcnt vmcnt(0)" ::: "memory");
  __syncthreads();
  for (int k0 = 0; k0 < 1024; k0 += 32) {
    int cur = (k0 >> 5) & 1;
    if (k0 + 32 < 1024) OSTAGE(k0 + 32, cur ^ 1);
    const char* Ab = (const char*)As + cur * 8192;
    const char* Bb = (const char*)Bs + cur * 8192;
    bf16x8 af[4], bfr[4];
#pragma unroll
    for (int i = 0; i < 4; ++i) af[i] = lds_frag(Ab, aoff[i]);
#pragma unroll
    for (int i = 0; i < 4; ++i) bfr[i] = lds_frag(Bb, boff[i]);
#pragma unroll
    for (int i = 0; i < 4; ++i)
#pragma unroll
      for (int jn = 0; jn < 4; ++jn) acc[i][jn] = MFMA(af[i], bfr[jn], acc[i][jn]);
    asm volatile("s_waitcnt vmcnt(0)" ::: "memory");
    __syncthreads();
  }
#undef OSTAGE

  int nb = n0 + wn * 64, mb = m0 + wm * 64;
#pragma unroll
  for (int i = 0; i < 4; ++i)
#pragma unroll
    for (int jn = 0; jn < 4; ++jn) {
      int n = nb + jn * 16 + (l & 15);
      float bsv = bo[n];
#pragma unroll
      for (int j = 0; j < 4; ++j) {
        int m = mb + i * 16 + ((l >> 4) << 2) + j;
        out[(size_t)m * 1024 + n] = acc[i][jn][j] + bsv;
      }
    }
}

extern "C" void kernel_launch(void* const* d_in, const int* in_sizes, int n_in,
                              void* d_out, int out_size, void* d_ws, size_t ws_size,
                              hipStream_t stream) {
  const float* x     = (const float*)d_in[0];
  // d_in[1] = mask (causal tril, implemented analytically)
  const float* freqs = (const float*)d_in[2];
  const float* Wq    = (const float*)d_in[3];
  const float* bq    = (const float*)d_in[4];
  const float* Wk    = (const float*)d_in[5];
  const float* bk    = (const float*)d_in[6];
  const float* Wv    = (const float*)d_in[7];
  const float* bv    = (const float*)d_in[8];
  const float* Wo    = (const float*)d_in[9];
  const float* bo    = (const float*)d_in[10];

  char* ws = (char*)d_ws;
  unsigned short* xb  = (unsigned short*)(ws);
  unsigned short* WT  = (unsigned short*)(ws + ((size_t)8 << 20));
  unsigned short* qb  = (unsigned short*)(ws + ((size_t)16 << 20));
  unsigned short* kb  = (unsigned short*)(ws + ((size_t)24 << 20));
  unsigned short* vtb = (unsigned short*)(ws + ((size_t)40 << 20));
  unsigned short* ab  = (unsigned short*)(ws + ((size_t)48 << 20));
  float*          tab = (float*)(ws + ((size_t)56 << 20));

  k_cast_x<<<2048, 256, 0, stream>>>(x, xb);
  k_trans_w<<<dim3(32, 32, 4), dim3(32, 8), 0, stream>>>(Wq, Wk, Wv, Wo, WT);
  k_cs<<<256, 256, 0, stream>>>(freqs, tab);
  k_qkv<<<dim3(8, 32, 3), 256, 0, stream>>>(xb, WT, bq, bk, bv, tab, qb, kb, vtb);
  k_attn<<<dim3(512), 256, 0, stream>>>(qb, kb, vtb, ab);
  k_oproj<<<dim3(8, 32), 256, 0, stream>>>(ab, WT + ((size_t)3 << 20), bo, (float*)d_out);
}

// Round 6
// 246.738 us; speedup vs baseline: 1.2559x; 1.1087x over previous
//
#include <hip/hip_runtime.h>
#include <cstdint>
#include <cstddef>

// Problem constants: B=2, T=2048, D=1024, H=16, HD=64
typedef __bf16 bf16x8 __attribute__((ext_vector_type(8)));
typedef float  f32x4  __attribute__((ext_vector_type(4)));

#define DEV __device__ __forceinline__

DEV unsigned short f2bf(float f) {
  union { float f; unsigned u; } x; x.f = f;
  unsigned r = x.u + 0x7fffu + ((x.u >> 16) & 1u);   // round-to-nearest-even
  return (unsigned short)(r >> 16);
}

DEV float fexp2(float x) {            // guaranteed single v_exp_f32 (2^x)
  float r;
  asm("v_exp_f32 %0, %1" : "=v"(r) : "v"(x));
  return r;
}

DEV void gl_lds16(const void* g, void* l) {
  __builtin_amdgcn_global_load_lds((const __attribute__((address_space(1))) void*)g,
                                   (__attribute__((address_space(3))) void*)l, 16, 0, 0);
}

DEV bf16x8 lds_frag(const void* base, int byteoff) {
  return *reinterpret_cast<const bf16x8*>(reinterpret_cast<const char*>(base) + byteoff);
}

DEV f32x4 MFMA(bf16x8 a, bf16x8 b, f32x4 c) {
  return __builtin_amdgcn_mfma_f32_16x16x32_bf16(a, b, c, 0, 0, 0);
}

#define KL2E 0.18033688011112042f     // log2(e)/sqrt(64), folded into Wq/bq

// ---------------- x -> bf16 ----------------
__global__ __launch_bounds__(256) void k_cast_x(const float* __restrict__ x,
                                                unsigned short* __restrict__ xb) {
  int i = (blockIdx.x * 256 + threadIdx.x) * 8;
  float4 a = *(const float4*)(x + i);
  float4 b = *(const float4*)(x + i + 4);
  uint4 o;
  o.x = (unsigned)f2bf(a.x) | ((unsigned)f2bf(a.y) << 16);
  o.y = (unsigned)f2bf(a.z) | ((unsigned)f2bf(a.w) << 16);
  o.z = (unsigned)f2bf(b.x) | ((unsigned)f2bf(b.y) << 16);
  o.w = (unsigned)f2bf(b.z) | ((unsigned)f2bf(b.w) << 16);
  *reinterpret_cast<uint4*>(xb + i) = o;
}

// ---------------- W (K x N, f32) -> W^T (N x K, bf16); Wq scaled by KL2E ----------------
__global__ __launch_bounds__(256) void k_trans_w(const float* __restrict__ Wq, const float* __restrict__ Wk,
                                                 const float* __restrict__ Wv, const float* __restrict__ Wo,
                                                 unsigned short* __restrict__ WT) {
  __shared__ float tile[32][33];
  int z = blockIdx.z;
  const float* W = (z == 0) ? Wq : ((z == 1) ? Wk : ((z == 2) ? Wv : Wo));
  float scl = (z == 0) ? KL2E : 1.0f;
  unsigned short* out = WT + ((size_t)z << 20);
  int x = threadIdx.x, y = threadIdx.y;        // block (32,8)
  int gx = blockIdx.x * 32 + x;                // col n
  int gy = blockIdx.y * 32;                    // row k base
#pragma unroll
  for (int i = 0; i < 4; ++i) tile[y + i * 8][x] = W[(size_t)(gy + y + i * 8) * 1024 + gx];
  __syncthreads();
#pragma unroll
  for (int i = 0; i < 4; ++i)
    out[(size_t)(blockIdx.x * 32 + y + i * 8) * 1024 + gy + x] = f2bf(tile[x][y + i * 8] * scl);
}

// ---------------- cos/sin table from freqs (T x 32) ----------------
__global__ __launch_bounds__(256) void k_cs(const float* __restrict__ freqs, float* __restrict__ tab) {
  int i = blockIdx.x * 256 + threadIdx.x;      // 0..65535
  float a = freqs[i];
  float s, c;
  sincosf(a, &s, &c);
  ((float2*)tab)[i] = make_float2(c, s);
}

// ---------------- QKV GEMM (dbuf): q/k with RoPE (q pre-scaled), v plain ----------------
__global__ __launch_bounds__(256) void k_qkv(const unsigned short* __restrict__ xb,
                                             const unsigned short* __restrict__ WT,
                                             const float* __restrict__ bq,
                                             const float* __restrict__ bk,
                                             const float* __restrict__ bv,
                                             const float* __restrict__ tab,
                                             unsigned short* __restrict__ qws,
                                             unsigned short* __restrict__ kws,
                                             unsigned short* __restrict__ vws) {
  __shared__ __align__(16) unsigned short As[2][128 * 32];
  __shared__ __align__(16) unsigned short Bs[2][128 * 32];
  int t = threadIdx.x, w = t >> 6, l = t & 63;
  int z = blockIdx.z;
  int n0 = blockIdx.x * 128, m0 = blockIdx.y * 128;
  const unsigned short* Wz = WT + ((size_t)z << 20);
  int wm = w >> 1, wn = w & 1;
  f32x4 zero4 = {0.f, 0.f, 0.f, 0.f};
  f32x4 acc[4][4];
#pragma unroll
  for (int i = 0; i < 4; ++i)
#pragma unroll
    for (int j = 0; j < 4; ++j) acc[i][j] = zero4;

  int aoff[4], boff[4];
#pragma unroll
  for (int i = 0; i < 4; ++i) {
    aoff[i] = ((wm * 64 + i * 16 + (l & 15)) * 32 + ((l >> 4) * 8)) * 2;
    boff[i] = ((wn * 64 + i * 16 + (l & 15)) * 32 + ((l >> 4) * 8)) * 2;
  }
  int r0 = t >> 2, c0 = t & 3;

#define QSTAGE(k0v, buf) do { \
    char* la = (char*)As + (buf) * 8192 + w * 1024; \
    char* lb = (char*)Bs + (buf) * 8192 + w * 1024; \
    const char* ga0 = (const char*)xb + ((size_t)(m0 + r0) * 1024 + (k0v) + c0 * 8) * 2; \
    const char* ga1 = (const char*)xb + ((size_t)(m0 + 64 + r0) * 1024 + (k0v) + c0 * 8) * 2; \
    const char* gb0 = (const char*)Wz + ((size_t)(n0 + r0) * 1024 + (k0v) + c0 * 8) * 2; \
    const char* gb1 = (const char*)Wz + ((size_t)(n0 + 64 + r0) * 1024 + (k0v) + c0 * 8) * 2; \
    gl_lds16(ga0, la); gl_lds16(ga1, la + 4096); \
    gl_lds16(gb0, lb); gl_lds16(gb1, lb + 4096); \
  } while (0)

  QSTAGE(0, 0);
  asm volatile("s_waitcnt vmcnt(0)" ::: "memory");
  __syncthreads();
  for (int k0 = 0; k0 < 1024; k0 += 32) {
    int cur = (k0 >> 5) & 1;
    if (k0 + 32 < 1024) QSTAGE(k0 + 32, cur ^ 1);
    const char* Ab = (const char*)As + cur * 8192;
    const char* Bb = (const char*)Bs + cur * 8192;
    bf16x8 af[4], bfr[4];
#pragma unroll
    for (int i = 0; i < 4; ++i) af[i] = lds_frag(Ab, aoff[i]);
#pragma unroll
    for (int i = 0; i < 4; ++i) bfr[i] = lds_frag(Bb, boff[i]);
#pragma unroll
    for (int i = 0; i < 4; ++i)
#pragma unroll
      for (int jn = 0; jn < 4; ++jn) acc[i][jn] = MFMA(af[i], bfr[jn], acc[i][jn]);
    asm volatile("s_waitcnt vmcnt(0)" ::: "memory");
    __syncthreads();
  }
#undef QSTAGE

  const float* bias = (z == 0) ? bq : ((z == 1) ? bk : bv);
  unsigned short* outp = (z == 0) ? qws : ((z == 1) ? kws : vws);
  float bscl = (z == 0) ? KL2E : 1.0f;
  bool doRope = (z < 2);
  int nb = n0 + wn * 64, mb = m0 + wm * 64;
#pragma unroll
  for (int i = 0; i < 4; ++i) {
#pragma unroll
    for (int jn = 0; jn < 4; ++jn) {
      int n = nb + jn * 16 + (l & 15);
      float bsv = bias[n] * bscl;
      int hd = n & 63;
#pragma unroll
      for (int j = 0; j < 4; ++j) {
        int m = mb + i * 16 + ((l >> 4) << 2) + j;
        float val = acc[i][jn][j] + bsv;
        if (doRope) {
          int trow = m & 2047;
          float2 cs = ((const float2*)tab)[trow * 32 + (hd >> 1)];
          float part = __shfl_xor(val, 1);
          val = (hd & 1) ? fmaf(part, cs.y, val * cs.x) : fmaf(val, cs.x, -part * cs.y);
        }
        ((__bf16*)outp)[(size_t)m * 1024 + n] = (__bf16)val;
      }
    }
  }
}

// ---------------- V (B,T,H,HD) -> V^T (B,H,HD,T) ----------------
__global__ __launch_bounds__(256) void k_vtrans(const unsigned short* __restrict__ vb,
                                                unsigned short* __restrict__ vtb) {
  __shared__ unsigned short vt[64 * 72];
  int t = threadIdx.x;
  int tt = blockIdx.x, bh = blockIdx.y;
  int b = bh >> 4, h = bh & 15;
  int row = t >> 2, ch = t & 3;
  const char* src = (const char*)vb + (((size_t)(b * 2048 + tt * 64 + row) * 1024) + h * 64 + ch * 16) * 2;
  uint4 v0 = *(const uint4*)src;
  uint4 v1 = *(const uint4*)(src + 16);
  const unsigned short* e0 = (const unsigned short*)&v0;
  const unsigned short* e1 = (const unsigned short*)&v1;
#pragma unroll
  for (int i = 0; i < 8; ++i) vt[(ch * 16 + i) * 72 + row] = e0[i];
#pragma unroll
  for (int i = 0; i < 8; ++i) vt[(ch * 16 + 8 + i) * 72 + row] = e1[i];
  __syncthreads();
  int hd = t >> 2, c2 = t & 3;
  uint4 o0 = *(const uint4*)&vt[hd * 72 + c2 * 16];
  uint4 o1 = *(const uint4*)&vt[hd * 72 + c2 * 16 + 8];
  char* dst = (char*)vtb + (((size_t)(bh * 64 + hd) * 2048) + tt * 64 + c2 * 16) * 2;
  *(uint4*)dst = o0;
  *(uint4*)(dst + 16) = o1;
}

// ---------------- attention strip: S in log2 units; no-max-sub fast path; lsum via ones-MFMA ----------------
DEV void attn_strip(const bf16x8 (&qf)[2], const bf16x8 (&kc)[2][4], const bf16x8 (&vc)[2][4],
                    f32x4 (&po)[4], f32x4 &lsum, float (&m_run)[4],
                    bool diag, unsigned short* pw, int w, int l) {
  int hi = l >> 4, lo = l & 15;
  f32x4 minit = {-m_run[0], -m_run[1], -m_run[2], -m_run[3]};
  f32x4 ps[4];
#pragma unroll
  for (int bn = 0; bn < 4; ++bn) ps[bn] = minit;  // C-init = -m  ->  ps = S - m
  __builtin_amdgcn_s_setprio(1);
#pragma unroll
  for (int ks = 0; ks < 2; ++ks)
#pragma unroll
    for (int bn = 0; bn < 4; ++bn) ps[bn] = MFMA(qf[ks], kc[ks][bn], ps[bn]);
  __builtin_amdgcn_s_setprio(0);
  if (diag) {
#pragma unroll
    for (int bn = 0; bn < 4; ++bn) {
      int kv = bn * 16 + lo;
#pragma unroll
      for (int j = 0; j < 4; ++j) {
        int r = (hi << 2) + j;
        if (kv > w * 16 + r) ps[bn][j] = -1e30f;
      }
    }
  }
  // lane-local max over this lane's 16 S' values; wave vote for the rare rescale path
  float t0 = fmaxf(fmaxf(ps[0][0], ps[0][1]), fmaxf(ps[0][2], ps[0][3]));
  float t1 = fmaxf(fmaxf(ps[1][0], ps[1][1]), fmaxf(ps[1][2], ps[1][3]));
  float t2 = fmaxf(fmaxf(ps[2][0], ps[2][1]), fmaxf(ps[2][2], ps[2][3]));
  float t3 = fmaxf(fmaxf(ps[3][0], ps[3][1]), fmaxf(ps[3][2], ps[3][3]));
  float tm = fmaxf(fmaxf(t0, t1), fmaxf(t2, t3));
  if (__any(tm > 8.0f)) {                       // slow path: exact row max + rescale
    float rm[4];
#pragma unroll
    for (int j = 0; j < 4; ++j)
      rm[j] = fmaxf(fmaxf(ps[0][j], ps[1][j]), fmaxf(ps[2][j], ps[3][j]));
#pragma unroll
    for (int off = 1; off < 16; off <<= 1)
#pragma unroll
      for (int j = 0; j < 4; ++j) rm[j] = fmaxf(rm[j], __shfl_xor(rm[j], off));
    float d[4], al[4];
#pragma unroll
    for (int j = 0; j < 4; ++j) {
      d[j] = fmaxf(rm[j], 0.f);
      al[j] = fexp2(-d[j]);
      m_run[j] += d[j];
    }
#pragma unroll
    for (int bn = 0; bn < 4; ++bn)
#pragma unroll
      for (int j = 0; j < 4; ++j) ps[bn][j] -= d[j];
#pragma unroll
    for (int hf = 0; hf < 4; ++hf)
#pragma unroll
      for (int j = 0; j < 4; ++j) po[hf][j] *= al[j];
#pragma unroll
    for (int j = 0; j < 4; ++j) lsum[j] *= al[j];
  }
  // P = 2^(S-m), bf16, to LDS (swizzled) for PV A-operand
#pragma unroll
  for (int bn = 0; bn < 4; ++bn)
#pragma unroll
    for (int j = 0; j < 4; ++j) {
      int r = (hi << 2) + j, c = bn * 16 + lo;
      ((__bf16*)pw)[r * 64 + (((c >> 3) ^ (r & 7)) << 3) + (c & 7)] = (__bf16)fexp2(ps[bn][j]);
    }
  asm volatile("" ::: "memory");
  __bf16 one = (__bf16)1.0f;
  bf16x8 ones = {one, one, one, one, one, one, one, one};
  __builtin_amdgcn_s_setprio(1);
#pragma unroll
  for (int ks = 0; ks < 2; ++ks) {
    bf16x8 pa = lds_frag(pw, lo * 128 + (((ks * 4 + hi) ^ (lo & 7)) << 4));
#pragma unroll
    for (int hf = 0; hf < 4; ++hf) po[hf] = MFMA(pa, vc[ks][hf], po[hf]);
    lsum = MFMA(pa, ones, lsum);               // row sums ride a ones-column MFMA
  }
  __builtin_amdgcn_s_setprio(0);
  asm volatile("" ::: "memory");
}

// ---------------- Flash attention (causal), paired strips, dbuf KV, XCD-clustered ----------------
__global__ __launch_bounds__(256) void k_attn(const unsigned short* __restrict__ qb,
                                              const unsigned short* __restrict__ kb,
                                              const unsigned short* __restrict__ vtb,
                                              unsigned short* __restrict__ ab) {
  __shared__ __align__(16) unsigned short Ks[2][64 * 64];
  __shared__ __align__(16) unsigned short Vts[2][64 * 64];
  __shared__ __align__(16) unsigned short PsA[4 * 16 * 64];
  __shared__ __align__(16) unsigned short PsB[4 * 16 * 64];
  int t = threadIdx.x, w = t >> 6, l = t & 63;
  int lid = blockIdx.x;                        // 512 blocks
  int xcd = lid & 7, rest = lid >> 3;          // cluster same-bh on one XCD's L2
  int bh = xcd + 8 * (rest & 3);
  int pi = rest >> 2;                          // 0..15
  int qtA = pi, qtB = 31 - pi;                 // balanced causal pair: 33 strip-tiles/block
  int b = bh >> 4, h = bh & 15;
  int hi = l >> 4, lo = l & 15;

  bf16x8 qfA[2], qfB[2];
  {
    int mA = b * 2048 + qtA * 64 + w * 16 + lo;
    const char* qp = (const char*)qb + ((size_t)mA * 1024 + h * 64 + hi * 8) * 2;
    qfA[0] = *(const bf16x8*)qp;
    qfA[1] = *(const bf16x8*)(qp + 64);
    int mB = b * 2048 + qtB * 64 + w * 16 + lo;
    const char* qp2 = (const char*)qb + ((size_t)mB * 1024 + h * 64 + hi * 8) * 2;
    qfB[0] = *(const bf16x8*)qp2;
    qfB[1] = *(const bf16x8*)(qp2 + 64);
  }
  f32x4 zero4 = {0.f, 0.f, 0.f, 0.f};
  f32x4 poA[4], poB[4], lsumA = zero4, lsumB = zero4;
  float mA_[4], mB_[4];
#pragma unroll
  for (int i = 0; i < 4; ++i) {
    poA[i] = zero4; poB[i] = zero4;
    mA_[i] = 0.f;  mB_[i] = 0.f;               // S' = S - 0; rescale path handles growth
  }
  unsigned short* pwA = PsA + w * 1024;
  unsigned short* pwB = PsB + w * 1024;
  int r0 = t >> 3, s0 = t & 7, lc0 = s0 ^ (r0 & 7);
  int r1 = 32 + r0;                            // (r1&7)==(r0&7) so lc1==lc0
  const char* kbase = (const char*)kb + ((size_t)(b * 2048) * 1024 + h * 64) * 2;
  const char* vbase = (const char*)vtb + ((size_t)bh * 64) * 2048 * 2;

#define ASTAGE(jt, buf) do { \
    char* lk = (char*)Ks + (buf) * 8192 + w * 1024; \
    char* lv = (char*)Vts + (buf) * 8192 + w * 1024; \
    const char* gk0 = kbase + ((size_t)((jt) * 64 + r0) * 1024) * 2 + lc0 * 16; \
    const char* gk1 = kbase + ((size_t)((jt) * 64 + r1) * 1024) * 2 + lc0 * 16; \
    const char* gv0 = vbase + (size_t)r0 * 4096 + (jt) * 128 + lc0 * 16; \
    const char* gv1 = vbase + (size_t)r1 * 4096 + (jt) * 128 + lc0 * 16; \
    gl_lds16(gk0, lk); gl_lds16(gk1, lk + 4096); \
    gl_lds16(gv0, lv); gl_lds16(gv1, lv + 4096); \
  } while (0)

  ASTAGE(0, 0);
  asm volatile("s_waitcnt vmcnt(0)" ::: "memory");
  __syncthreads();
  for (int jt = 0; jt <= qtB; ++jt) {
    int cur = jt & 1;
    if (jt < qtB) ASTAGE(jt + 1, cur ^ 1);     // prefetch overlaps compute below
    const char* Kb = (const char*)Ks + cur * 8192;
    const char* Vb = (const char*)Vts + cur * 8192;
    // cache K/V fragments in registers; shared by both strips
    bf16x8 kc[2][4], vc[2][4];
#pragma unroll
    for (int ks = 0; ks < 2; ++ks)
#pragma unroll
      for (int i = 0; i < 4; ++i) {
        int row = i * 16 + lo;
        kc[ks][i] = lds_frag(Kb, row * 128 + (((ks * 4 + hi) ^ (lo & 7)) << 4));
        vc[ks][i] = lds_frag(Vb, row * 128 + (((ks * 4 + hi) ^ (lo & 7)) << 4));
      }
    attn_strip(qfB, kc, vc, poB, lsumB, mB_, jt == qtB, pwB, w, l);
    if (jt <= qtA) attn_strip(qfA, kc, vc, poA, lsumA, mA_, jt == qtA, pwA, w, l);
    asm volatile("s_waitcnt vmcnt(0)" ::: "memory");
    __syncthreads();
  }
#undef ASTAGE

#pragma unroll
  for (int s = 0; s < 2; ++s) {
    f32x4* po = s ? poB : poA;
    f32x4 ls = s ? lsumB : lsumA;
    int qt = s ? qtB : qtA;
    float inv[4];
#pragma unroll
    for (int j = 0; j < 4; ++j) inv[j] = 1.0f / ls[j];
#pragma unroll
    for (int hf = 0; hf < 4; ++hf)
#pragma unroll
      for (int j = 0; j < 4; ++j) {
        int r = (hi << 2) + j;
        int m = b * 2048 + qt * 64 + w * 16 + r;
        int col = h * 64 + hf * 16 + lo;
        ((__bf16*)ab)[(size_t)m * 1024 + col] = (__bf16)(po[hf][j] * inv[j]);
      }
  }
}

// ---------------- Output projection (dbuf): ab @ Wo + bo -> fp32 out ----------------
__global__ __launch_bounds__(256) void k_oproj(const unsigned short* __restrict__ ab,
                                               const unsigned short* __restrict__ WoT,
                                               const float* __restrict__ bo,
                                               float* __restrict__ out) {
  __shared__ __align__(16) unsigned short As[2][128 * 32];
  __shared__ __align__(16) unsigned short Bs[2][128 * 32];
  int t = threadIdx.x, w = t >> 6, l = t & 63;
  int n0 = blockIdx.x * 128, m0 = blockIdx.y * 128;
  int wm = w >> 1, wn = w & 1;
  f32x4 zero4 = {0.f, 0.f, 0.f, 0.f};
  f32x4 acc[4][4];
#pragma unroll
  for (int i = 0; i < 4; ++i)
#pragma unroll
    for (int j = 0; j < 4; ++j) acc[i][j] = zero4;
  int aoff[4], boff[4];
#pragma unroll
  for (int i = 0; i < 4; ++i) {
    aoff[i] = ((wm * 64 + i * 16 + (l & 15)) * 32 + ((l >> 4) * 8)) * 2;
    boff[i] = ((wn * 64 + i * 16 + (l & 15)) * 32 + ((l >> 4) * 8)) * 2;
  }
  int r0 = t >> 2, c0 = t & 3;

#define OSTAGE(k0v, buf) do { \
    char* la = (char*)As + (buf) * 8192 + w * 1024; \
    char* lb = (char*)Bs + (buf) * 8192 + w * 1024; \
    const char* ga0 = (const char*)ab + ((size_t)(m0 + r0) * 1024 + (k0v) + c0 * 8) * 2; \
    const char* ga1 = (const char*)ab + ((size_t)(m0 + 64 + r0) * 1024 + (k0v) + c0 * 8) * 2; \
    const char* gb0 = (const char*)WoT + ((size_t)(n0 + r0) * 1024 + (k0v) + c0 * 8) * 2; \
    const char* gb1 = (const char*)WoT + ((size_t)(n0 + 64 + r0) * 1024 + (k0v) + c0 * 8) * 2; \
    gl_lds16(ga0, la); gl_lds16(ga1, la + 4096); \
    gl_lds16(gb0, lb); gl_lds16(gb1, lb + 4096); \
  } while (0)

  OSTAGE(0, 0);
  asm volatile("s_waitcnt vmcnt(0)" ::: "memory");
  __syncthreads();
  for (int k0 = 0; k0 < 1024; k0 += 32) {
    int cur = (k0 >> 5) & 1;
    if (k0 + 32 < 1024) OSTAGE(k0 + 32, cur ^ 1);
    const char* Ab = (const char*)As + cur * 8192;
    const char* Bb = (const char*)Bs + cur * 8192;
    bf16x8 af[4], bfr[4];
#pragma unroll
    for (int i = 0; i < 4; ++i) af[i] = lds_frag(Ab, aoff[i]);
#pragma unroll
    for (int i = 0; i < 4; ++i) bfr[i] = lds_frag(Bb, boff[i]);
#pragma unroll
    for (int i = 0; i < 4; ++i)
#pragma unroll
      for (int jn = 0; jn < 4; ++jn) acc[i][jn] = MFMA(af[i], bfr[jn], acc[i][jn]);
    asm volatile("s_waitcnt vmcnt(0)" ::: "memory");
    __syncthreads();
  }
#undef OSTAGE

  int nb = n0 + wn * 64, mb = m0 + wm * 64;
#pragma unroll
  for (int i = 0; i < 4; ++i)
#pragma unroll
    for (int jn = 0; jn < 4; ++jn) {
      int n = nb + jn * 16 + (l & 15);
      float bsv = bo[n];
#pragma unroll
      for (int j = 0; j < 4; ++j) {
        int m = mb + i * 16 + ((l >> 4) << 2) + j;
        out[(size_t)m * 1024 + n] = acc[i][jn][j] + bsv;
      }
    }
}

extern "C" void kernel_launch(void* const* d_in, const int* in_sizes, int n_in,
                              void* d_out, int out_size, void* d_ws, size_t ws_size,
                              hipStream_t stream) {
  const float* x     = (const float*)d_in[0];
  // d_in[1] = mask (causal tril, implemented analytically)
  const float* freqs = (const float*)d_in[2];
  const float* Wq    = (const float*)d_in[3];
  const float* bq    = (const float*)d_in[4];
  const float* Wk    = (const float*)d_in[5];
  const float* bk    = (const float*)d_in[6];
  const float* Wv    = (const float*)d_in[7];
  const float* bv    = (const float*)d_in[8];
  const float* Wo    = (const float*)d_in[9];
  const float* bo    = (const float*)d_in[10];

  char* ws = (char*)d_ws;
  unsigned short* xb  = (unsigned short*)(ws);
  unsigned short* WT  = (unsigned short*)(ws + ((size_t)8 << 20));
  unsigned short* qb  = (unsigned short*)(ws + ((size_t)16 << 20));
  unsigned short* kb  = (unsigned short*)(ws + ((size_t)24 << 20));
  unsigned short* vb  = (unsigned short*)(ws + ((size_t)32 << 20));
  unsigned short* vtb = (unsigned short*)(ws + ((size_t)40 << 20));
  unsigned short* ab  = (unsigned short*)(ws + ((size_t)48 << 20));
  float*          tab = (float*)(ws + ((size_t)56 << 20));

  k_cast_x<<<2048, 256, 0, stream>>>(x, xb);
  k_trans_w<<<dim3(32, 32, 4), dim3(32, 8), 0, stream>>>(Wq, Wk, Wv, Wo, WT);
  k_cs<<<256, 256, 0, stream>>>(freqs, tab);
  k_qkv<<<dim3(8, 32, 3), 256, 0, stream>>>(xb, WT, bq, bk, bv, tab, qb, kb, vb);
  k_vtrans<<<dim3(32, 32), 256, 0, stream>>>(vb, vtb);
  k_attn<<<dim3(512), 256, 0, stream>>>(qb, kb, vtb, ab);
  k_oproj<<<dim3(8, 32), 256, 0, stream>>>(ab, WT + ((size_t)3 << 20), bo, (float*)d_out);
}

// Round 9
// 245.420 us; speedup vs baseline: 1.2627x; 1.0054x over previous
//
#include <hip/hip_runtime.h>
#include <cstdint>
#include <cstddef>

// Problem constants: B=2, T=2048, D=1024, H=16, HD=64
typedef __bf16 bf16x8 __attribute__((ext_vector_type(8)));
typedef float  f32x4  __attribute__((ext_vector_type(4)));

#define DEV __device__ __forceinline__

DEV unsigned short f2bf(float f) {
  union { float f; unsigned u; } x; x.f = f;
  unsigned r = x.u + 0x7fffu + ((x.u >> 16) & 1u);   // round-to-nearest-even
  return (unsigned short)(r >> 16);
}

DEV float fexp2(float x) {            // guaranteed single v_exp_f32 (2^x)
  float r;
  asm("v_exp_f32 %0, %1" : "=v"(r) : "v"(x));
  return r;
}

DEV void gl_lds16(const void* g, void* l) {
  __builtin_amdgcn_global_load_lds((const __attribute__((address_space(1))) void*)g,
                                   (__attribute__((address_space(3))) void*)l, 16, 0, 0);
}

DEV bf16x8 lds_frag(const void* base, int byteoff) {
  return *reinterpret_cast<const bf16x8*>(reinterpret_cast<const char*>(base) + byteoff);
}

DEV f32x4 MFMA(bf16x8 a, bf16x8 b, f32x4 c) {
  return __builtin_amdgcn_mfma_f32_16x16x32_bf16(a, b, c, 0, 0, 0);
}

#define KL2E 0.18033688011112042f     // log2(e)/sqrt(64), folded into Wq/bq
#define BARRIER __builtin_amdgcn_s_barrier()

// ---------------- x -> bf16 ----------------
__global__ __launch_bounds__(256) void k_cast_x(const float* __restrict__ x,
                                                unsigned short* __restrict__ xb) {
  int i = (blockIdx.x * 256 + threadIdx.x) * 8;
  float4 a = *(const float4*)(x + i);
  float4 b = *(const float4*)(x + i + 4);
  uint4 o;
  o.x = (unsigned)f2bf(a.x) | ((unsigned)f2bf(a.y) << 16);
  o.y = (unsigned)f2bf(a.z) | ((unsigned)f2bf(a.w) << 16);
  o.z = (unsigned)f2bf(b.x) | ((unsigned)f2bf(b.y) << 16);
  o.w = (unsigned)f2bf(b.z) | ((unsigned)f2bf(b.w) << 16);
  *reinterpret_cast<uint4*>(xb + i) = o;
}

// ---------------- W (K x N, f32) -> W^T (N x K, bf16); Wq scaled by KL2E ----------------
__global__ __launch_bounds__(256) void k_trans_w(const float* __restrict__ Wq, const float* __restrict__ Wk,
                                                 const float* __restrict__ Wv, const float* __restrict__ Wo,
                                                 unsigned short* __restrict__ WT) {
  __shared__ float tile[32][33];
  int z = blockIdx.z;
  const float* W = (z == 0) ? Wq : ((z == 1) ? Wk : ((z == 2) ? Wv : Wo));
  float scl = (z == 0) ? KL2E : 1.0f;
  unsigned short* out = WT + ((size_t)z << 20);
  int x = threadIdx.x, y = threadIdx.y;        // block (32,8)
  int gx = blockIdx.x * 32 + x;                // col n
  int gy = blockIdx.y * 32;                    // row k base
#pragma unroll
  for (int i = 0; i < 4; ++i) tile[y + i * 8][x] = W[(size_t)(gy + y + i * 8) * 1024 + gx];
  __syncthreads();
#pragma unroll
  for (int i = 0; i < 4; ++i)
    out[(size_t)(blockIdx.x * 32 + y + i * 8) * 1024 + gy + x] = f2bf(tile[x][y + i * 8] * scl);
}

// ---------------- cos/sin table from freqs (T x 32) ----------------
__global__ __launch_bounds__(256) void k_cs(const float* __restrict__ freqs, float* __restrict__ tab) {
  int i = blockIdx.x * 256 + threadIdx.x;      // 0..65535
  float a = freqs[i];
  float s, c;
  sincosf(a, &s, &c);
  ((float2*)tab)[i] = make_float2(c, s);
}

// ---------------- QKV GEMM (counted-vmcnt dbuf): q/k with RoPE (q pre-scaled), v plain ----------------
__global__ __launch_bounds__(256) void k_qkv(const unsigned short* __restrict__ xb,
                                             const unsigned short* __restrict__ WT,
                                             const float* __restrict__ bq,
                                             const float* __restrict__ bk,
                                             const float* __restrict__ bv,
                                             const float* __restrict__ tab,
                                             unsigned short* __restrict__ qws,
                                             unsigned short* __restrict__ kws,
                                             unsigned short* __restrict__ vws) {
  __shared__ __align__(16) unsigned short As[2][128 * 32];
  __shared__ __align__(16) unsigned short Bs[2][128 * 32];
  int t = threadIdx.x, w = t >> 6, l = t & 63;
  int z = blockIdx.z;
  int n0 = blockIdx.x * 128, m0 = blockIdx.y * 128;
  const unsigned short* Wz = WT + ((size_t)z << 20);
  int wm = w >> 1, wn = w & 1;
  f32x4 zero4 = {0.f, 0.f, 0.f, 0.f};
  f32x4 acc[4][4];
#pragma unroll
  for (int i = 0; i < 4; ++i)
#pragma unroll
    for (int j = 0; j < 4; ++j) acc[i][j] = zero4;

  int aoff[4], boff[4];
#pragma unroll
  for (int i = 0; i < 4; ++i) {
    aoff[i] = ((wm * 64 + i * 16 + (l & 15)) * 32 + ((l >> 4) * 8)) * 2;
    boff[i] = ((wn * 64 + i * 16 + (l & 15)) * 32 + ((l >> 4) * 8)) * 2;
  }
  int r0 = t >> 2, c0 = t & 3;

#define QSTAGE(k0v, buf) do { \
    char* la = (char*)As + (buf) * 8192 + w * 1024; \
    char* lb = (char*)Bs + (buf) * 8192 + w * 1024; \
    const char* ga0 = (const char*)xb + ((size_t)(m0 + r0) * 1024 + (k0v) + c0 * 8) * 2; \
    const char* ga1 = (const char*)xb + ((size_t)(m0 + 64 + r0) * 1024 + (k0v) + c0 * 8) * 2; \
    const char* gb0 = (const char*)Wz + ((size_t)(n0 + r0) * 1024 + (k0v) + c0 * 8) * 2; \
    const char* gb1 = (const char*)Wz + ((size_t)(n0 + 64 + r0) * 1024 + (k0v) + c0 * 8) * 2; \
    gl_lds16(ga0, la); gl_lds16(ga1, la + 4096); \
    gl_lds16(gb0, lb); gl_lds16(gb1, lb + 4096); \
  } while (0)

  QSTAGE(0, 0);
  asm volatile("s_waitcnt vmcnt(0)" ::: "memory");
  BARRIER;
  for (int k0 = 0; k0 < 1024; k0 += 32) {
    int cur = (k0 >> 5) & 1;
    if (k0 + 32 < 1024) {
      QSTAGE(k0 + 32, cur ^ 1);                       // prefetch stays in flight across the barrier
      asm volatile("s_waitcnt vmcnt(4)" ::: "memory"); // wait only for tile-k0's 4 loads (T4)
    } else {
      asm volatile("s_waitcnt vmcnt(0)" ::: "memory");
    }
    BARRIER;
    const char* Ab = (const char*)As + cur * 8192;
    const char* Bb = (const char*)Bs + cur * 8192;
    bf16x8 af[4], bfr[4];
#pragma unroll
    for (int i = 0; i < 4; ++i) af[i] = lds_frag(Ab, aoff[i]);
#pragma unroll
    for (int i = 0; i < 4; ++i) bfr[i] = lds_frag(Bb, boff[i]);
#pragma unroll
    for (int i = 0; i < 4; ++i)
#pragma unroll
      for (int jn = 0; jn < 4; ++jn) acc[i][jn] = MFMA(af[i], bfr[jn], acc[i][jn]);
    BARRIER;                                          // reads done before next iter's stage overwrites
  }
#undef QSTAGE

  const float* bias = (z == 0) ? bq : ((z == 1) ? bk : bv);
  unsigned short* outp = (z == 0) ? qws : ((z == 1) ? kws : vws);
  float bscl = (z == 0) ? KL2E : 1.0f;
  bool doRope = (z < 2);
  int nb = n0 + wn * 64, mb = m0 + wm * 64;
#pragma unroll
  for (int i = 0; i < 4; ++i) {
#pragma unroll
    for (int jn = 0; jn < 4; ++jn) {
      int n = nb + jn * 16 + (l & 15);
      float bsv = bias[n] * bscl;
      int hd = n & 63;
#pragma unroll
      for (int j = 0; j < 4; ++j) {
        int m = mb + i * 16 + ((l >> 4) << 2) + j;
        float val = acc[i][jn][j] + bsv;
        if (doRope) {
          int trow = m & 2047;
          float2 cs = ((const float2*)tab)[trow * 32 + (hd >> 1)];
          float part = __shfl_xor(val, 1);
          val = (hd & 1) ? fmaf(part, cs.y, val * cs.x) : fmaf(val, cs.x, -part * cs.y);
        }
        ((__bf16*)outp)[(size_t)m * 1024 + n] = (__bf16)val;
      }
    }
  }
}

// ---------------- V (B,T,H,HD) -> V^T (B,H,HD,T) ----------------
__global__ __launch_bounds__(256) void k_vtrans(const unsigned short* __restrict__ vb,
                                                unsigned short* __restrict__ vtb) {
  __shared__ unsigned short vt[64 * 72];
  int t = threadIdx.x;
  int tt = blockIdx.x, bh = blockIdx.y;
  int b = bh >> 4, h = bh & 15;
  int row = t >> 2, ch = t & 3;
  const char* src = (const char*)vb + (((size_t)(b * 2048 + tt * 64 + row) * 1024) + h * 64 + ch * 16) * 2;
  uint4 v0 = *(const uint4*)src;
  uint4 v1 = *(const uint4*)(src + 16);
  const unsigned short* e0 = (const unsigned short*)&v0;
  const unsigned short* e1 = (const unsigned short*)&v1;
#pragma unroll
  for (int i = 0; i < 8; ++i) vt[(ch * 16 + i) * 72 + row] = e0[i];
#pragma unroll
  for (int i = 0; i < 8; ++i) vt[(ch * 16 + 8 + i) * 72 + row] = e1[i];
  __syncthreads();
  int hd = t >> 2, c2 = t & 3;
  uint4 o0 = *(const uint4*)&vt[hd * 72 + c2 * 16];
  uint4 o1 = *(const uint4*)&vt[hd * 72 + c2 * 16 + 8];
  char* dst = (char*)vtb + (((size_t)(bh * 64 + hd) * 2048) + tt * 64 + c2 * 16) * 2;
  *(uint4*)dst = o0;
  *(uint4*)(dst + 16) = o1;
}

// ---------------- attention strip: S in log2 units; no-max-sub fast path; lsum via ones-MFMA ----------------
DEV void attn_strip(const bf16x8 (&qf)[2], const bf16x8 (&kc)[2][4], const bf16x8 (&vc)[2][4],
                    f32x4 (&po)[4], f32x4 &lsum, float (&m_run)[4],
                    bool diag, unsigned short* pw, int w, int l) {
  int hi = l >> 4, lo = l & 15;
  f32x4 minit = {-m_run[0], -m_run[1], -m_run[2], -m_run[3]};
  f32x4 ps[4];
#pragma unroll
  for (int bn = 0; bn < 4; ++bn) ps[bn] = minit;  // C-init = -m  ->  ps = S - m
  __builtin_amdgcn_s_setprio(1);
#pragma unroll
  for (int ks = 0; ks < 2; ++ks)
#pragma unroll
    for (int bn = 0; bn < 4; ++bn) ps[bn] = MFMA(qf[ks], kc[ks][bn], ps[bn]);
  __builtin_amdgcn_s_setprio(0);
  if (diag) {
#pragma unroll
    for (int bn = 0; bn < 4; ++bn) {
      int kv = bn * 16 + lo;
#pragma unroll
      for (int j = 0; j < 4; ++j) {
        int r = (hi << 2) + j;
        if (kv > w * 16 + r) ps[bn][j] = -1e30f;
      }
    }
  }
  // lane-local max over this lane's 16 S' values; wave vote for the rare rescale path
  float t0 = fmaxf(fmaxf(ps[0][0], ps[0][1]), fmaxf(ps[0][2], ps[0][3]));
  float t1 = fmaxf(fmaxf(ps[1][0], ps[1][1]), fmaxf(ps[1][2], ps[1][3]));
  float t2 = fmaxf(fmaxf(ps[2][0], ps[2][1]), fmaxf(ps[2][2], ps[2][3]));
  float t3 = fmaxf(fmaxf(ps[3][0], ps[3][1]), fmaxf(ps[3][2], ps[3][3]));
  float tm = fmaxf(fmaxf(t0, t1), fmaxf(t2, t3));
  if (__any(tm > 8.0f)) {                       // slow path: exact row max + rescale
    float rm[4];
#pragma unroll
    for (int j = 0; j < 4; ++j)
      rm[j] = fmaxf(fmaxf(ps[0][j], ps[1][j]), fmaxf(ps[2][j], ps[3][j]));
#pragma unroll
    for (int off = 1; off < 16; off <<= 1)
#pragma unroll
      for (int j = 0; j < 4; ++j) rm[j] = fmaxf(rm[j], __shfl_xor(rm[j], off));
    float d[4], al[4];
#pragma unroll
    for (int j = 0; j < 4; ++j) {
      d[j] = fmaxf(rm[j], 0.f);
      al[j] = fexp2(-d[j]);
      m_run[j] += d[j];
    }
#pragma unroll
    for (int bn = 0; bn < 4; ++bn)
#pragma unroll
      for (int j = 0; j < 4; ++j) ps[bn][j] -= d[j];
#pragma unroll
    for (int hf = 0; hf < 4; ++hf)
#pragma unroll
      for (int j = 0; j < 4; ++j) po[hf][j] *= al[j];
#pragma unroll
    for (int j = 0; j < 4; ++j) lsum[j] *= al[j];
  }
  // P = 2^(S-m), bf16, to LDS (swizzled) for PV A-operand
#pragma unroll
  for (int bn = 0; bn < 4; ++bn)
#pragma unroll
    for (int j = 0; j < 4; ++j) {
      int r = (hi << 2) + j, c = bn * 16 + lo;
      ((__bf16*)pw)[r * 64 + (((c >> 3) ^ (r & 7)) << 3) + (c & 7)] = (__bf16)fexp2(ps[bn][j]);
    }
  asm volatile("" ::: "memory");
  __bf16 one = (__bf16)1.0f;
  bf16x8 ones = {one, one, one, one, one, one, one, one};
  __builtin_amdgcn_s_setprio(1);
#pragma unroll
  for (int ks = 0; ks < 2; ++ks) {
    bf16x8 pa = lds_frag(pw, lo * 128 + (((ks * 4 + hi) ^ (lo & 7)) << 4));
#pragma unroll
    for (int hf = 0; hf < 4; ++hf) po[hf] = MFMA(pa, vc[ks][hf], po[hf]);
    lsum = MFMA(pa, ones, lsum);               // row sums ride a ones-column MFMA
  }
  __builtin_amdgcn_s_setprio(0);
  asm volatile("" ::: "memory");
}

// ---------------- Flash attention (causal), paired strips, counted-vmcnt dbuf KV, XCD-clustered ----------------
__global__ __launch_bounds__(256) void k_attn(const unsigned short* __restrict__ qb,
                                              const unsigned short* __restrict__ kb,
                                              const unsigned short* __restrict__ vtb,
                                              unsigned short* __restrict__ ab) {
  __shared__ __align__(16) unsigned short Ks[2][64 * 64];
  __shared__ __align__(16) unsigned short Vts[2][64 * 64];
  __shared__ __align__(16) unsigned short PsA[4 * 16 * 64];
  __shared__ __align__(16) unsigned short PsB[4 * 16 * 64];
  int t = threadIdx.x, w = t >> 6, l = t & 63;
  int lid = blockIdx.x;                        // 512 blocks
  int xcd = lid & 7, rest = lid >> 3;          // cluster same-bh on one XCD's L2
  int bh = xcd + 8 * (rest & 3);
  int pi = rest >> 2;                          // 0..15
  int qtA = pi, qtB = 31 - pi;                 // balanced causal pair: 33 strip-tiles/block
  int b = bh >> 4, h = bh & 15;
  int hi = l >> 4, lo = l & 15;

  bf16x8 qfA[2], qfB[2];
  {
    int mA = b * 2048 + qtA * 64 + w * 16 + lo;
    const char* qp = (const char*)qb + ((size_t)mA * 1024 + h * 64 + hi * 8) * 2;
    qfA[0] = *(const bf16x8*)qp;
    qfA[1] = *(const bf16x8*)(qp + 64);
    int mB = b * 2048 + qtB * 64 + w * 16 + lo;
    const char* qp2 = (const char*)qb + ((size_t)mB * 1024 + h * 64 + hi * 8) * 2;
    qfB[0] = *(const bf16x8*)qp2;
    qfB[1] = *(const bf16x8*)(qp2 + 64);
  }
  f32x4 zero4 = {0.f, 0.f, 0.f, 0.f};
  f32x4 poA[4], poB[4], lsumA = zero4, lsumB = zero4;
  float mA_[4], mB_[4];
#pragma unroll
  for (int i = 0; i < 4; ++i) {
    poA[i] = zero4; poB[i] = zero4;
    mA_[i] = 0.f;  mB_[i] = 0.f;               // S' = S - 0; rescale path handles growth
  }
  unsigned short* pwA = PsA + w * 1024;
  unsigned short* pwB = PsB + w * 1024;
  int r0 = t >> 3, s0 = t & 7, lc0 = s0 ^ (r0 & 7);
  int r1 = 32 + r0;                            // (r1&7)==(r0&7) so lc1==lc0
  const char* kbase = (const char*)kb + ((size_t)(b * 2048) * 1024 + h * 64) * 2;
  const char* vbase = (const char*)vtb + ((size_t)bh * 64) * 2048 * 2;

#define ASTAGE(jt, buf) do { \
    char* lk = (char*)Ks + (buf) * 8192 + w * 1024; \
    char* lv = (char*)Vts + (buf) * 8192 + w * 1024; \
    const char* gk0 = kbase + ((size_t)((jt) * 64 + r0) * 1024) * 2 + lc0 * 16; \
    const char* gk1 = kbase + ((size_t)((jt) * 64 + r1) * 1024) * 2 + lc0 * 16; \
    const char* gv0 = vbase + (size_t)r0 * 4096 + (jt) * 128 + lc0 * 16; \
    const char* gv1 = vbase + (size_t)r1 * 4096 + (jt) * 128 + lc0 * 16; \
    gl_lds16(gk0, lk); gl_lds16(gk1, lk + 4096); \
    gl_lds16(gv0, lv); gl_lds16(gv1, lv + 4096); \
  } while (0)

  ASTAGE(0, 0);
  asm volatile("s_waitcnt vmcnt(0)" ::: "memory");
  BARRIER;
  for (int jt = 0; jt <= qtB; ++jt) {
    int cur = jt & 1;
    if (jt < qtB) {
      ASTAGE(jt + 1, cur ^ 1);                        // prefetch stays in flight across barrier
      asm volatile("s_waitcnt vmcnt(4)" ::: "memory"); // only wait for tile-jt's 4 loads
    } else {
      asm volatile("s_waitcnt vmcnt(0)" ::: "memory");
    }
    BARRIER;
    const char* Kb = (const char*)Ks + cur * 8192;
    const char* Vb = (const char*)Vts + cur * 8192;
    // cache K/V fragments in registers; shared by both strips
    bf16x8 kc[2][4], vc[2][4];
#pragma unroll
    for (int ks = 0; ks < 2; ++ks)
#pragma unroll
      for (int i = 0; i < 4; ++i) {
        int row = i * 16 + lo;
        kc[ks][i] = lds_frag(Kb, row * 128 + (((ks * 4 + hi) ^ (lo & 7)) << 4));
        vc[ks][i] = lds_frag(Vb, row * 128 + (((ks * 4 + hi) ^ (lo & 7)) << 4));
      }
    attn_strip(qfB, kc, vc, poB, lsumB, mB_, jt == qtB, pwB, w, l);
    if (jt <= qtA) attn_strip(qfA, kc, vc, poA, lsumA, mA_, jt == qtA, pwA, w, l);
    BARRIER;                                          // LDS reads done before next stage overwrites
  }
#undef ASTAGE

#pragma unroll
  for (int s = 0; s < 2; ++s) {
    f32x4* po = s ? poB : poA;
    f32x4 ls = s ? lsumB : lsumA;
    int qt = s ? qtB : qtA;
    float inv[4];
#pragma unroll
    for (int j = 0; j < 4; ++j) inv[j] = 1.0f / ls[j];
#pragma unroll
    for (int hf = 0; hf < 4; ++hf)
#pragma unroll
      for (int j = 0; j < 4; ++j) {
        int r = (hi << 2) + j;
        int m = b * 2048 + qt * 64 + w * 16 + r;
        int col = h * 64 + hf * 16 + lo;
        ((__bf16*)ab)[(size_t)m * 1024 + col] = (__bf16)(po[hf][j] * inv[j]);
      }
  }
}

// ---------------- Output projection: 64x128 tile, 512 blocks, counted-vmcnt dbuf ----------------
__global__ __launch_bounds__(256) void k_oproj(const unsigned short* __restrict__ ab,
                                               const unsigned short* __restrict__ WoT,
                                               const float* __restrict__ bo,
                                               float* __restrict__ out) {
  __shared__ __align__(16) unsigned short As[2][64 * 32];
  __shared__ __align__(16) unsigned short Bs[2][128 * 32];
  int t = threadIdx.x, w = t >> 6, l = t & 63;
  int n0 = blockIdx.x * 128, m0 = blockIdx.y * 64;
  int wm = w >> 1, wn = w & 1;                 // waves 2x2: each 32 rows x 64 cols
  f32x4 zero4 = {0.f, 0.f, 0.f, 0.f};
  f32x4 acc[2][4];
#pragma unroll
  for (int i = 0; i < 2; ++i)
#pragma unroll
    for (int j = 0; j < 4; ++j) acc[i][j] = zero4;
  int aoff[2], boff[4];
#pragma unroll
  for (int i = 0; i < 2; ++i)
    aoff[i] = ((wm * 32 + i * 16 + (l & 15)) * 32 + ((l >> 4) * 8)) * 2;
#pragma unroll
  for (int i = 0; i < 4; ++i)
    boff[i] = ((wn * 64 + i * 16 + (l & 15)) * 32 + ((l >> 4) * 8)) * 2;
  int ra = t >> 2, ca = t & 3;                 // A: 64 rows x 4 chunks = 256 = 1/thread

#define OSTAGE(k0v, buf) do { \
    char* la = (char*)As + (buf) * 4096; \
    char* lb = (char*)Bs + (buf) * 8192; \
    const char* ga = (const char*)ab + ((size_t)(m0 + ra) * 1024 + (k0v) + ca * 8) * 2; \
    const char* gb0 = (const char*)WoT + ((size_t)(n0 + ra) * 1024 + (k0v) + ca * 8) * 2; \
    const char* gb1 = (const char*)WoT + ((size_t)(n0 + 64 + ra) * 1024 + (k0v) + ca * 8) * 2; \
    gl_lds16(ga, la + t * 16); \
    gl_lds16(gb0, lb + t * 16); \
    gl_lds16(gb1, lb + 4096 + t * 16); \
  } while (0)

  OSTAGE(0, 0);
  asm volatile("s_waitcnt vmcnt(0)" ::: "memory");
  BARRIER;
  for (int k0 = 0; k0 < 1024; k0 += 32) {
    int cur = (k0 >> 5) & 1;
    if (k0 + 32 < 1024) {
      OSTAGE(k0 + 32, cur ^ 1);
      asm volatile("s_waitcnt vmcnt(3)" ::: "memory"); // 3 loads/thread per stage
    } else {
      asm volatile("s_waitcnt vmcnt(0)" ::: "memory");
    }
    BARRIER;
    const char* Ab = (const char*)As + cur * 4096;
    const char* Bb = (const char*)Bs + cur * 8192;
    bf16x8 af[2], bfr[4];
#pragma unroll
    for (int i = 0; i < 2; ++i) af[i] = lds_frag(Ab, aoff[i]);
#pragma unroll
    for (int i = 0; i < 4; ++i) bfr[i] = lds_frag(Bb, boff[i]);
#pragma unroll
    for (int i = 0; i < 2; ++i)
#pragma unroll
      for (int jn = 0; jn < 4; ++jn) acc[i][jn] = MFMA(af[i], bfr[jn], acc[i][jn]);
    BARRIER;
  }
#undef OSTAGE

  int nb = n0 + wn * 64, mb = m0 + wm * 32;
#pragma unroll
  for (int i = 0; i < 2; ++i)
#pragma unroll
    for (int jn = 0; jn < 4; ++jn) {
      int n = nb + jn * 16 + (l & 15);
      float bsv = bo[n];
#pragma unroll
      for (int j = 0; j < 4; ++j) {
        int m = mb + i * 16 + ((l >> 4) << 2) + j;
        out[(size_t)m * 1024 + n] = acc[i][jn][j] + bsv;
      }
    }
}

extern "C" void kernel_launch(void* const* d_in, const int* in_sizes, int n_in,
                              void* d_out, int out_size, void* d_ws, size_t ws_size,
                              hipStream_t stream) {
  const float* x     = (const float*)d_in[0];
  // d_in[1] = mask (causal tril, implemented analytically)
  const float* freqs = (const float*)d_in[2];
  const float* Wq    = (const float*)d_in[3];
  const float* bq    = (const float*)d_in[4];
  const float* Wk    = (const float*)d_in[5];
  const float* bk    = (const float*)d_in[6];
  const float* Wv    = (const float*)d_in[7];
  const float* bv    = (const float*)d_in[8];
  const float* Wo    = (const float*)d_in[9];
  const float* bo    = (const float*)d_in[10];

  char* ws = (char*)d_ws;
  unsigned short* xb  = (unsigned short*)(ws);
  unsigned short* WT  = (unsigned short*)(ws + ((size_t)8 << 20));
  unsigned short* qb  = (unsigned short*)(ws + ((size_t)16 << 20));
  unsigned short* kb  = (unsigned short*)(ws + ((size_t)24 << 20));
  unsigned short* vb  = (unsigned short*)(ws + ((size_t)32 << 20));
  unsigned short* vtb = (unsigned short*)(ws + ((size_t)40 << 20));
  unsigned short* ab  = (unsigned short*)(ws + ((size_t)48 << 20));
  float*          tab = (float*)(ws + ((size_t)56 << 20));

  k_cast_x<<<2048, 256, 0, stream>>>(x, xb);
  k_trans_w<<<dim3(32, 32, 4), dim3(32, 8), 0, stream>>>(Wq, Wk, Wv, Wo, WT);
  k_cs<<<256, 256, 0, stream>>>(freqs, tab);
  k_qkv<<<dim3(8, 32, 3), 256, 0, stream>>>(xb, WT, bq, bk, bv, tab, qb, kb, vb);
  k_vtrans<<<dim3(32, 32), 256, 0, stream>>>(vb, vtb);
  k_attn<<<dim3(512), 256, 0, stream>>>(qb, kb, vtb, ab);
  k_oproj<<<dim3(8, 64), 256, 0, stream>>>(ab, WT + ((size_t)3 << 20), bo, (float*)d_out);
}

// Round 10
// 222.362 us; speedup vs baseline: 1.3936x; 1.1037x over previous
//
#include <hip/hip_runtime.h>
#include <cstdint>
#include <cstddef>

// Problem constants: B=2, T=2048, D=1024, H=16, HD=64
typedef __bf16 bf16x8 __attribute__((ext_vector_type(8)));
typedef float  f32x4  __attribute__((ext_vector_type(4)));

#define DEV __device__ __forceinline__

DEV unsigned short f2bf(float f) {
  union { float f; unsigned u; } x; x.f = f;
  unsigned r = x.u + 0x7fffu + ((x.u >> 16) & 1u);   // round-to-nearest-even
  return (unsigned short)(r >> 16);
}

DEV float fexp2(float x) {            // guaranteed single v_exp_f32 (2^x)
  float r;
  asm("v_exp_f32 %0, %1" : "=v"(r) : "v"(x));
  return r;
}

DEV unsigned cvtpk(float lo, float hi) {  // packs lo->bits[15:0], hi->bits[31:16]
  unsigned r;
  asm("v_cvt_pk_bf16_f32 %0, %1, %2" : "=v"(r) : "v"(lo), "v"(hi));
  return r;
}

DEV void gl_lds16(const void* g, void* l) {
  __builtin_amdgcn_global_load_lds((const __attribute__((address_space(1))) void*)g,
                                   (__attribute__((address_space(3))) void*)l, 16, 0, 0);
}

DEV bf16x8 lds_frag(const void* base, int byteoff) {
  return *reinterpret_cast<const bf16x8*>(reinterpret_cast<const char*>(base) + byteoff);
}

DEV f32x4 MFMA(bf16x8 a, bf16x8 b, f32x4 c) {
  return __builtin_amdgcn_mfma_f32_16x16x32_bf16(a, b, c, 0, 0, 0);
}

#define KL2E 0.18033688011112042f     // log2(e)/sqrt(64), folded into Wq/bq
#define BARRIER __builtin_amdgcn_s_barrier()

// ---------------- x -> bf16 ----------------
__global__ __launch_bounds__(256) void k_cast_x(const float* __restrict__ x,
                                                unsigned short* __restrict__ xb) {
  int i = (blockIdx.x * 256 + threadIdx.x) * 8;
  float4 a = *(const float4*)(x + i);
  float4 b = *(const float4*)(x + i + 4);
  uint4 o;
  o.x = (unsigned)f2bf(a.x) | ((unsigned)f2bf(a.y) << 16);
  o.y = (unsigned)f2bf(a.z) | ((unsigned)f2bf(a.w) << 16);
  o.z = (unsigned)f2bf(b.x) | ((unsigned)f2bf(b.y) << 16);
  o.w = (unsigned)f2bf(b.z) | ((unsigned)f2bf(b.w) << 16);
  *reinterpret_cast<uint4*>(xb + i) = o;
}

// ---------------- W (K x N, f32) -> W^T (N x K, bf16); Wq scaled by KL2E ----------------
__global__ __launch_bounds__(256) void k_trans_w(const float* __restrict__ Wq, const float* __restrict__ Wk,
                                                 const float* __restrict__ Wv, const float* __restrict__ Wo,
                                                 unsigned short* __restrict__ WT) {
  __shared__ float tile[32][33];
  int z = blockIdx.z;
  const float* W = (z == 0) ? Wq : ((z == 1) ? Wk : ((z == 2) ? Wv : Wo));
  float scl = (z == 0) ? KL2E : 1.0f;
  unsigned short* out = WT + ((size_t)z << 20);
  int x = threadIdx.x, y = threadIdx.y;        // block (32,8)
  int gx = blockIdx.x * 32 + x;                // col n
  int gy = blockIdx.y * 32;                    // row k base
#pragma unroll
  for (int i = 0; i < 4; ++i) tile[y + i * 8][x] = W[(size_t)(gy + y + i * 8) * 1024 + gx];
  __syncthreads();
#pragma unroll
  for (int i = 0; i < 4; ++i)
    out[(size_t)(blockIdx.x * 32 + y + i * 8) * 1024 + gy + x] = f2bf(tile[x][y + i * 8] * scl);
}

// ---------------- cos/sin table from freqs (T x 32) ----------------
__global__ __launch_bounds__(256) void k_cs(const float* __restrict__ freqs, float* __restrict__ tab) {
  int i = blockIdx.x * 256 + threadIdx.x;      // 0..65535
  float a = freqs[i];
  float s, c;
  sincosf(a, &s, &c);
  ((float2*)tab)[i] = make_float2(c, s);
}

// ---------------- QKV GEMM (counted-vmcnt dbuf): q/k with RoPE (q pre-scaled), v plain ----------------
__global__ __launch_bounds__(256) void k_qkv(const unsigned short* __restrict__ xb,
                                             const unsigned short* __restrict__ WT,
                                             const float* __restrict__ bq,
                                             const float* __restrict__ bk,
                                             const float* __restrict__ bv,
                                             const float* __restrict__ tab,
                                             unsigned short* __restrict__ qws,
                                             unsigned short* __restrict__ kws,
                                             unsigned short* __restrict__ vws) {
  __shared__ __align__(16) unsigned short As[2][128 * 32];
  __shared__ __align__(16) unsigned short Bs[2][128 * 32];
  int t = threadIdx.x, w = t >> 6, l = t & 63;
  int z = blockIdx.z;
  int n0 = blockIdx.x * 128, m0 = blockIdx.y * 128;
  const unsigned short* Wz = WT + ((size_t)z << 20);
  int wm = w >> 1, wn = w & 1;
  f32x4 zero4 = {0.f, 0.f, 0.f, 0.f};
  f32x4 acc[4][4];
#pragma unroll
  for (int i = 0; i < 4; ++i)
#pragma unroll
    for (int j = 0; j < 4; ++j) acc[i][j] = zero4;

  int aoff[4], boff[4];
#pragma unroll
  for (int i = 0; i < 4; ++i) {
    aoff[i] = ((wm * 64 + i * 16 + (l & 15)) * 32 + ((l >> 4) * 8)) * 2;
    boff[i] = ((wn * 64 + i * 16 + (l & 15)) * 32 + ((l >> 4) * 8)) * 2;
  }
  int r0 = t >> 2, c0 = t & 3;

#define QSTAGE(k0v, buf) do { \
    char* la = (char*)As + (buf) * 8192 + w * 1024; \
    char* lb = (char*)Bs + (buf) * 8192 + w * 1024; \
    const char* ga0 = (const char*)xb + ((size_t)(m0 + r0) * 1024 + (k0v) + c0 * 8) * 2; \
    const char* ga1 = (const char*)xb + ((size_t)(m0 + 64 + r0) * 1024 + (k0v) + c0 * 8) * 2; \
    const char* gb0 = (const char*)Wz + ((size_t)(n0 + r0) * 1024 + (k0v) + c0 * 8) * 2; \
    const char* gb1 = (const char*)Wz + ((size_t)(n0 + 64 + r0) * 1024 + (k0v) + c0 * 8) * 2; \
    gl_lds16(ga0, la); gl_lds16(ga1, la + 4096); \
    gl_lds16(gb0, lb); gl_lds16(gb1, lb + 4096); \
  } while (0)

  QSTAGE(0, 0);
  asm volatile("s_waitcnt vmcnt(0)" ::: "memory");
  BARRIER;
  for (int k0 = 0; k0 < 1024; k0 += 32) {
    int cur = (k0 >> 5) & 1;
    if (k0 + 32 < 1024) {
      QSTAGE(k0 + 32, cur ^ 1);
      asm volatile("s_waitcnt vmcnt(4)" ::: "memory");
    } else {
      asm volatile("s_waitcnt vmcnt(0)" ::: "memory");
    }
    BARRIER;
    const char* Ab = (const char*)As + cur * 8192;
    const char* Bb = (const char*)Bs + cur * 8192;
    bf16x8 af[4], bfr[4];
#pragma unroll
    for (int i = 0; i < 4; ++i) af[i] = lds_frag(Ab, aoff[i]);
#pragma unroll
    for (int i = 0; i < 4; ++i) bfr[i] = lds_frag(Bb, boff[i]);
#pragma unroll
    for (int i = 0; i < 4; ++i)
#pragma unroll
      for (int jn = 0; jn < 4; ++jn) acc[i][jn] = MFMA(af[i], bfr[jn], acc[i][jn]);
    BARRIER;
  }
#undef QSTAGE

  const float* bias = (z == 0) ? bq : ((z == 1) ? bk : bv);
  unsigned short* outp = (z == 0) ? qws : ((z == 1) ? kws : vws);
  float bscl = (z == 0) ? KL2E : 1.0f;
  bool doRope = (z < 2);
  int nb = n0 + wn * 64, mb = m0 + wm * 64;
#pragma unroll
  for (int i = 0; i < 4; ++i) {
#pragma unroll
    for (int jn = 0; jn < 4; ++jn) {
      int n = nb + jn * 16 + (l & 15);
      float bsv = bias[n] * bscl;
      int hd = n & 63;
#pragma unroll
      for (int j = 0; j < 4; ++j) {
        int m = mb + i * 16 + ((l >> 4) << 2) + j;
        float val = acc[i][jn][j] + bsv;
        if (doRope) {
          int trow = m & 2047;
          float2 cs = ((const float2*)tab)[trow * 32 + (hd >> 1)];
          float part = __shfl_xor(val, 1);
          val = (hd & 1) ? fmaf(part, cs.y, val * cs.x) : fmaf(val, cs.x, -part * cs.y);
        }
        ((__bf16*)outp)[(size_t)m * 1024 + n] = (__bf16)val;
      }
    }
  }
}

// ---------------- V (B,T,H,HD) -> V^T (B,H,HD,T) ----------------
__global__ __launch_bounds__(256) void k_vtrans(const unsigned short* __restrict__ vb,
                                                unsigned short* __restrict__ vtb) {
  __shared__ unsigned short vt[64 * 72];
  int t = threadIdx.x;
  int tt = blockIdx.x, bh = blockIdx.y;
  int b = bh >> 4, h = bh & 15;
  int row = t >> 2, ch = t & 3;
  const char* src = (const char*)vb + (((size_t)(b * 2048 + tt * 64 + row) * 1024) + h * 64 + ch * 16) * 2;
  uint4 v0 = *(const uint4*)src;
  uint4 v1 = *(const uint4*)(src + 16);
  const unsigned short* e0 = (const unsigned short*)&v0;
  const unsigned short* e1 = (const unsigned short*)&v1;
#pragma unroll
  for (int i = 0; i < 8; ++i) vt[(ch * 16 + i) * 72 + row] = e0[i];
#pragma unroll
  for (int i = 0; i < 8; ++i) vt[(ch * 16 + 8 + i) * 72 + row] = e1[i];
  __syncthreads();
  int hd = t >> 2, c2 = t & 3;
  uint4 o0 = *(const uint4*)&vt[hd * 72 + c2 * 16];
  uint4 o1 = *(const uint4*)&vt[hd * 72 + c2 * 16 + 8];
  char* dst = (char*)vtb + (((size_t)(bh * 64 + hd) * 2048) + tt * 64 + c2 * 16) * 2;
  *(uint4*)dst = o0;
  *(uint4*)(dst + 16) = o1;
}

// ---------------- Flash attention: swapped QK^T & PV, P in registers, 1 q-tile/block ----------------
// ps[bn] = mfma(K,Q): lane holds q-row (l&15); kv = bn*16 + hi*4 + reg.
// PV: po[hf] = mfma(V^T, P): P redistributed to B-operand layout via cvt_pk + shfl.
__global__ __launch_bounds__(256) void k_attn(const unsigned short* __restrict__ qb,
                                              const unsigned short* __restrict__ kb,
                                              const unsigned short* __restrict__ vtb,
                                              unsigned short* __restrict__ ab) {
  __shared__ __align__(16) unsigned short Ks[2][64 * 64];
  __shared__ __align__(16) unsigned short Vts[2][64 * 64];
  int t = threadIdx.x, w = t >> 6, l = t & 63;
  int lo = l & 15, hi = l >> 4;
  int lid = blockIdx.x;                        // 1024 blocks
  int xcd = lid & 7;
  int bh = xcd + 8 * ((lid >> 3) & 3);         // same-bh clustered per XCD
  int qt = 31 - (lid >> 5);                    // heavy-first dispatch
  int b = bh >> 4, h = bh & 15;

  bf16x8 qf[2];
  {
    int m = b * 2048 + qt * 64 + w * 16 + lo;
    const char* qp = (const char*)qb + ((size_t)m * 1024 + h * 64 + hi * 8) * 2;
    qf[0] = *(const bf16x8*)qp;
    qf[1] = *(const bf16x8*)(qp + 64);
  }
  f32x4 zero4 = {0.f, 0.f, 0.f, 0.f};
  f32x4 po[4], lsum = zero4;
  float m_run = 0.f;                           // per-lane: one q-row
#pragma unroll
  for (int i = 0; i < 4; ++i) po[i] = zero4;

  int r0 = t >> 3, s0 = t & 7, lc0 = s0 ^ (r0 & 7);
  int r1 = 32 + r0;                            // (r1&7)==(r0&7) so same swizzle
  const char* kbase = (const char*)kb + ((size_t)(b * 2048) * 1024 + h * 64) * 2;
  const char* vbase = (const char*)vtb + ((size_t)bh * 64) * 2048 * 2;
  __bf16 one = (__bf16)1.0f;
  bf16x8 ones = {one, one, one, one, one, one, one, one};

#define ASTAGE(jt, buf) do { \
    char* lk = (char*)Ks + (buf) * 8192 + w * 1024; \
    char* lv = (char*)Vts + (buf) * 8192 + w * 1024; \
    const char* gk0 = kbase + ((size_t)((jt) * 64 + r0) * 1024) * 2 + lc0 * 16; \
    const char* gk1 = kbase + ((size_t)((jt) * 64 + r1) * 1024) * 2 + lc0 * 16; \
    const char* gv0 = vbase + (size_t)r0 * 4096 + (jt) * 128 + lc0 * 16; \
    const char* gv1 = vbase + (size_t)r1 * 4096 + (jt) * 128 + lc0 * 16; \
    gl_lds16(gk0, lk); gl_lds16(gk1, lk + 4096); \
    gl_lds16(gv0, lv); gl_lds16(gv1, lv + 4096); \
  } while (0)

  ASTAGE(0, 0);
  asm volatile("s_waitcnt vmcnt(0)" ::: "memory");
  BARRIER;
  for (int jt = 0; jt <= qt; ++jt) {
    int cur = jt & 1;
    if (jt < qt) {
      ASTAGE(jt + 1, cur ^ 1);                        // prefetch stays in flight
      asm volatile("s_waitcnt vmcnt(4)" ::: "memory");
    } else {
      asm volatile("s_waitcnt vmcnt(0)" ::: "memory");
    }
    BARRIER;
    const char* Kb = (const char*)Ks + cur * 8192;
    const char* Vb = (const char*)Vts + cur * 8192;

    // ---- swapped QK^T: ps[bn][j] = S'[q=lo][kv=bn*16+hi*4+j] - m_run ----
    f32x4 ps[4];
#pragma unroll
    for (int bn = 0; bn < 4; ++bn) ps[bn] = (f32x4){-m_run, -m_run, -m_run, -m_run};
    __builtin_amdgcn_s_setprio(1);
#pragma unroll
    for (int ks = 0; ks < 2; ++ks)
#pragma unroll
      for (int bn = 0; bn < 4; ++bn) {
        bf16x8 kcf = lds_frag(Kb, (bn * 16 + lo) * 128 + (((ks * 4 + hi) ^ (lo & 7)) << 4));
        ps[bn] = MFMA(kcf, qf[ks], ps[bn]);
      }
    __builtin_amdgcn_s_setprio(0);
    if (jt == qt) {                              // causal mask on diagonal tile
      int qrow = w * 16 + lo;
#pragma unroll
      for (int bn = 0; bn < 4; ++bn)
#pragma unroll
        for (int j = 0; j < 4; ++j)
          if (bn * 16 + hi * 4 + j > qrow) ps[bn][j] = -1e30f;
    }
    // lane-local max of this lane's 16 values; wave vote for rare rescale
    float tm = ps[0][0];
#pragma unroll
    for (int bn = 0; bn < 4; ++bn)
#pragma unroll
      for (int j = 0; j < 4; ++j) tm = fmaxf(tm, ps[bn][j]);
    if (__any(tm > 8.0f)) {                      // slow path: exact row max + rescale
      float rm = fmaxf(tm, __shfl_xor(tm, 16));
      rm = fmaxf(rm, __shfl_xor(rm, 32));
      float d = fmaxf(rm, 0.f);
      float al = fexp2(-d);
      m_run += d;
#pragma unroll
      for (int bn = 0; bn < 4; ++bn)
#pragma unroll
        for (int j = 0; j < 4; ++j) ps[bn][j] -= d;
#pragma unroll
      for (int hf = 0; hf < 4; ++hf)
#pragma unroll
        for (int j = 0; j < 4; ++j) po[hf][j] *= al;
#pragma unroll
      for (int j = 0; j < 4; ++j) lsum[j] *= al;
    }
    // P = 2^(S'), packed bf16 pairs: p2[bn][jp] = (kv 2jp, 2jp+1) of block bn
    unsigned p2[4][2];
#pragma unroll
    for (int bn = 0; bn < 4; ++bn) {
      p2[bn][0] = cvtpk(fexp2(ps[bn][0]), fexp2(ps[bn][1]));
      p2[bn][1] = cvtpk(fexp2(ps[bn][2]), fexp2(ps[bn][3]));
    }
    // ---- swapped PV: redistribute P to B-operand layout via shfl ----
    int srcA = lo + 32 * (hi & 1);               // lane of srcHi = 2*(hi&1)
    int srcB = srcA + 16;                        // srcHi + 1
    __builtin_amdgcn_s_setprio(1);
#pragma unroll
    for (int ks = 0; ks < 2; ++ks) {
      unsigned a0 = __shfl(p2[2 * ks][0], srcA), a1 = __shfl(p2[2 * ks][1], srcA);
      unsigned a2 = __shfl(p2[2 * ks][0], srcB), a3 = __shfl(p2[2 * ks][1], srcB);
      unsigned b0 = __shfl(p2[2 * ks + 1][0], srcA), b1 = __shfl(p2[2 * ks + 1][1], srcA);
      unsigned b2 = __shfl(p2[2 * ks + 1][0], srcB), b3 = __shfl(p2[2 * ks + 1][1], srcB);
      uint4 wv;
      wv.x = (hi < 2) ? a0 : b0;
      wv.y = (hi < 2) ? a1 : b1;
      wv.z = (hi < 2) ? a2 : b2;
      wv.w = (hi < 2) ? a3 : b3;
      bf16x8 pb;
      __builtin_memcpy(&pb, &wv, 16);
#pragma unroll
      for (int hf = 0; hf < 4; ++hf) {
        bf16x8 vcf = lds_frag(Vb, (hf * 16 + lo) * 128 + (((ks * 4 + hi) ^ (lo & 7)) << 4));
        po[hf] = MFMA(vcf, pb, po[hf]);
      }
      lsum = MFMA(ones, pb, lsum);               // row sums ride a ones-A MFMA
    }
    __builtin_amdgcn_s_setprio(0);
    BARRIER;                                     // LDS reads done before next stage overwrites
  }
#undef ASTAGE

  // epilogue: po[hf][j] holds O^T: row dd = hf*16+hi*4+j, col q = lo
  float inv = 1.0f / lsum[0];
  int m = b * 2048 + qt * 64 + w * 16 + lo;
#pragma unroll
  for (int hf = 0; hf < 4; ++hf) {
    ushort4 pk;
    pk.x = f2bf(po[hf][0] * inv);
    pk.y = f2bf(po[hf][1] * inv);
    pk.z = f2bf(po[hf][2] * inv);
    pk.w = f2bf(po[hf][3] * inv);
    *(ushort4*)&ab[(size_t)m * 1024 + h * 64 + hf * 16 + hi * 4] = pk;
  }
}

// ---------------- Output projection: 64x128 tile, 512 blocks, counted-vmcnt dbuf ----------------
__global__ __launch_bounds__(256) void k_oproj(const unsigned short* __restrict__ ab,
                                               const unsigned short* __restrict__ WoT,
                                               const float* __restrict__ bo,
                                               float* __restrict__ out) {
  __shared__ __align__(16) unsigned short As[2][64 * 32];
  __shared__ __align__(16) unsigned short Bs[2][128 * 32];
  int t = threadIdx.x, w = t >> 6, l = t & 63;
  int n0 = blockIdx.x * 128, m0 = blockIdx.y * 64;
  int wm = w >> 1, wn = w & 1;                 // waves 2x2: each 32 rows x 64 cols
  f32x4 zero4 = {0.f, 0.f, 0.f, 0.f};
  f32x4 acc[2][4];
#pragma unroll
  for (int i = 0; i < 2; ++i)
#pragma unroll
    for (int j = 0; j < 4; ++j) acc[i][j] = zero4;
  int aoff[2], boff[4];
#pragma unroll
  for (int i = 0; i < 2; ++i)
    aoff[i] = ((wm * 32 + i * 16 + (l & 15)) * 32 + ((l >> 4) * 8)) * 2;
#pragma unroll
  for (int i = 0; i < 4; ++i)
    boff[i] = ((wn * 64 + i * 16 + (l & 15)) * 32 + ((l >> 4) * 8)) * 2;
  int ra = t >> 2, ca = t & 3;

#define OSTAGE(k0v, buf) do { \
    char* la = (char*)As + (buf) * 4096; \
    char* lb = (char*)Bs + (buf) * 8192; \
    const char* ga = (const char*)ab + ((size_t)(m0 + ra) * 1024 + (k0v) + ca * 8) * 2; \
    const char* gb0 = (const char*)WoT + ((size_t)(n0 + ra) * 1024 + (k0v) + ca * 8) * 2; \
    const char* gb1 = (const char*)WoT + ((size_t)(n0 + 64 + ra) * 1024 + (k0v) + ca * 8) * 2; \
    gl_lds16(ga, la + t * 16); \
    gl_lds16(gb0, lb + t * 16); \
    gl_lds16(gb1, lb + 4096 + t * 16); \
  } while (0)

  OSTAGE(0, 0);
  asm volatile("s_waitcnt vmcnt(0)" ::: "memory");
  BARRIER;
  for (int k0 = 0; k0 < 1024; k0 += 32) {
    int cur = (k0 >> 5) & 1;
    if (k0 + 32 < 1024) {
      OSTAGE(k0 + 32, cur ^ 1);
      asm volatile("s_waitcnt vmcnt(3)" ::: "memory");
    } else {
      asm volatile("s_waitcnt vmcnt(0)" ::: "memory");
    }
    BARRIER;
    const char* Ab = (const char*)As + cur * 4096;
    const char* Bb = (const char*)Bs + cur * 8192;
    bf16x8 af[2], bfr[4];
#pragma unroll
    for (int i = 0; i < 2; ++i) af[i] = lds_frag(Ab, aoff[i]);
#pragma unroll
    for (int i = 0; i < 4; ++i) bfr[i] = lds_frag(Bb, boff[i]);
#pragma unroll
    for (int i = 0; i < 2; ++i)
#pragma unroll
      for (int jn = 0; jn < 4; ++jn) acc[i][jn] = MFMA(af[i], bfr[jn], acc[i][jn]);
    BARRIER;
  }
#undef OSTAGE

  int nb = n0 + wn * 64, mb = m0 + wm * 32;
#pragma unroll
  for (int i = 0; i < 2; ++i)
#pragma unroll
    for (int jn = 0; jn < 4; ++jn) {
      int n = nb + jn * 16 + (l & 15);
      float bsv = bo[n];
#pragma unroll
      for (int j = 0; j < 4; ++j) {
        int m = mb + i * 16 + ((l >> 4) << 2) + j;
        out[(size_t)m * 1024 + n] = acc[i][jn][j] + bsv;
      }
    }
}

extern "C" void kernel_launch(void* const* d_in, const int* in_sizes, int n_in,
                              void* d_out, int out_size, void* d_ws, size_t ws_size,
                              hipStream_t stream) {
  const float* x     = (const float*)d_in[0];
  // d_in[1] = mask (causal tril, implemented analytically)
  const float* freqs = (const float*)d_in[2];
  const float* Wq    = (const float*)d_in[3];
  const float* bq    = (const float*)d_in[4];
  const float* Wk    = (const float*)d_in[5];
  const float* bk    = (const float*)d_in[6];
  const float* Wv    = (const float*)d_in[7];
  const float* bv    = (const float*)d_in[8];
  const float* Wo    = (const float*)d_in[9];
  const float* bo    = (const float*)d_in[10];

  char* ws = (char*)d_ws;
  unsigned short* xb  = (unsigned short*)(ws);
  unsigned short* WT  = (unsigned short*)(ws + ((size_t)8 << 20));
  unsigned short* qb  = (unsigned short*)(ws + ((size_t)16 << 20));
  unsigned short* kb  = (unsigned short*)(ws + ((size_t)24 << 20));
  unsigned short* vb  = (unsigned short*)(ws + ((size_t)32 << 20));
  unsigned short* vtb = (unsigned short*)(ws + ((size_t)40 << 20));
  unsigned short* ab  = (unsigned short*)(ws + ((size_t)48 << 20));
  float*          tab = (float*)(ws + ((size_t)56 << 20));

  k_cast_x<<<2048, 256, 0, stream>>>(x, xb);
  k_trans_w<<<dim3(32, 32, 4), dim3(32, 8), 0, stream>>>(Wq, Wk, Wv, Wo, WT);
  k_cs<<<256, 256, 0, stream>>>(freqs, tab);
  k_qkv<<<dim3(8, 32, 3), 256, 0, stream>>>(xb, WT, bq, bk, bv, tab, qb, kb, vb);
  k_vtrans<<<dim3(32, 32), 256, 0, stream>>>(vb, vtb);
  k_attn<<<dim3(1024), 256, 0, stream>>>(qb, kb, vtb, ab);
  k_oproj<<<dim3(8, 64), 256, 0, stream>>>(ab, WT + ((size_t)3 << 20), bo, (float*)d_out);
}